// Round 3
// baseline (1027.483 us; speedup 1.0000x reference)
//
#include <hip/hip_runtime.h>

constexpr int kN    = 100000;   // nodes
constexpr int kE    = 1600000;  // random edges
constexpr int kTotE = kE + kN;  // + self loops
constexpr int kM    = 20000;    // masked rows
constexpr float kSlope = 0.2f;

typedef short short8  __attribute__((ext_vector_type(8)));
typedef float floatx4 __attribute__((ext_vector_type(4)));

__device__ __forceinline__ float bf2f(unsigned short u) {
  union { unsigned int i; float f; } v; v.i = ((unsigned int)u) << 16; return v.f;
}
__device__ __forceinline__ unsigned short f2bf(float f) {
  union { float f; unsigned int i; } v; v.f = f;
  unsigned int x = v.i;
  x += 0x7fffu + ((x >> 16) & 1u);   // RNE
  return (unsigned short)(x >> 16);
}
__device__ __forceinline__ short8 pack8(float4 u, float4 v) {
  short8 r;
  r[0] = (short)f2bf(u.x); r[1] = (short)f2bf(u.y);
  r[2] = (short)f2bf(u.z); r[3] = (short)f2bf(u.w);
  r[4] = (short)f2bf(v.x); r[5] = (short)f2bf(v.y);
  r[6] = (short)f2bf(v.z); r[7] = (short)f2bf(v.w);
  return r;
}

// ---------------- CSR build ----------------
__global__ void k_init_counts(int* counts) {
  int i = blockIdx.x * 256 + threadIdx.x;
  if (i < kN) counts[i] = 1;              // self-loop
}

__global__ void k_count(const int* __restrict__ dst, int* __restrict__ counts) {
  int i = blockIdx.x * 256 + threadIdx.x;
  if (i < kE) atomicAdd(&counts[dst[i]], 1);
}

// NOTE: cursor may alias counts (each thread reads its own chunk before writing it)
__global__ __launch_bounds__(1024) void k_scan(const int* counts,
                                               int* row_start,
                                               int* cursor) {
  __shared__ int sums[1024];
  int t = threadIdx.x;
  const int chunk = (kN + 1023) >> 10;    // 98
  int begin = t * chunk;
  int end = begin + chunk; if (end > kN) end = kN;
  int cnt[98];
  int s = 0;
  if (begin < kN) {
    for (int i = begin; i < end; ++i) { cnt[i - begin] = counts[i]; s += cnt[i - begin]; }
  }
  sums[t] = s;
  __syncthreads();
  for (int off = 1; off < 1024; off <<= 1) {   // Hillis-Steele inclusive scan
    int v = (t >= off) ? sums[t - off] : 0;
    __syncthreads();
    sums[t] += v;
    __syncthreads();
  }
  int run = (t == 0) ? 0 : sums[t - 1];
  if (begin < kN) {
    for (int i = begin; i < end; ++i) {
      row_start[i] = run; cursor[i] = run; run += cnt[i - begin];
    }
  }
  if (t == 1023) row_start[kN] = sums[1023];
}

__global__ void k_fill(const int* __restrict__ src, const int* __restrict__ dst,
                       int* __restrict__ cursor, int* __restrict__ col) {
  int i = blockIdx.x * 256 + threadIdx.x;
  if (i >= kTotE) return;
  int s, d;
  if (i < kE) { s = src[i]; d = dst[i]; }
  else        { s = d = i - kE; }
  int pos = atomicAdd(&cursor[d], 1);
  col[pos] = s;
}

// ---------------- weight pre-swizzle (fp32 -> bf16) into MFMA B-frag order ----------------
// Wf[((kt*NT + nt)*64 + lane)*8 + j] = bf16(W[(kt*32 + quad*8 + j)*Fo + nt*16 + (lane&15)])
__global__ void k_wprep(const float* __restrict__ W,
                        unsigned short* __restrict__ Wf, int K, int Fo) {
  int idx = blockIdx.x * 256 + threadIdx.x;
  if (idx >= K * Fo) return;
  int j    = idx & 7;
  int lane = (idx >> 3) & 63;
  int t    = idx >> 9;
  int NT = Fo >> 4;
  int kt = t / NT, nt = t - kt * NT;
  int k = kt * 32 + ((lane >> 4) & 3) * 8 + j;
  int n = nt * 16 + (lane & 15);
  Wf[idx] = f2bf(W[k * Fo + n]);
}

// ---------------- GEMM layer1: h1[N,128](bf16) = x(fp32) @ W1, + alpha dots (fp32) ----------------
__global__ __launch_bounds__(256) void k_gemm1(const float* __restrict__ x,
                                               const unsigned short* __restrict__ Wf,
                                               const float* __restrict__ asrc,
                                               const float* __restrict__ adst,
                                               unsigned short* __restrict__ h1,
                                               float* __restrict__ as, float* __restrict__ ad) {
  __shared__ unsigned short tile[4][16 * 128];   // 16 KB, per-wave regions
  int wave = threadIdx.x >> 6, lane = threadIdx.x & 63;
  int strip = blockIdx.x * 4 + wave;
  if (strip >= kN / 16) return;
  int r0 = strip * 16;
  int m = lane & 15, quad = lane >> 4;
  const float4* xf = (const float4*)(x + (size_t)(r0 + m) * 128);   // 32 float4 per row
  short8 a0 = pack8(xf[quad * 2 + 0],  xf[quad * 2 + 1]);           // k-tile 0
  short8 a1 = pack8(xf[quad * 2 + 8],  xf[quad * 2 + 9]);           // k-tile 1
  short8 a2 = pack8(xf[quad * 2 + 16], xf[quad * 2 + 17]);          // k-tile 2
  short8 a3 = pack8(xf[quad * 2 + 24], xf[quad * 2 + 25]);          // k-tile 3
  const short8* wf = (const short8*)Wf;
  floatx4 acc[8];
#pragma unroll
  for (int nt = 0; nt < 8; ++nt) acc[nt] = floatx4{0.f, 0.f, 0.f, 0.f};
#pragma unroll
  for (int nt = 0; nt < 8; ++nt) {
    acc[nt] = __builtin_amdgcn_mfma_f32_16x16x32_bf16(a0, wf[(0 * 8 + nt) * 64 + lane], acc[nt], 0, 0, 0);
    acc[nt] = __builtin_amdgcn_mfma_f32_16x16x32_bf16(a1, wf[(1 * 8 + nt) * 64 + lane], acc[nt], 0, 0, 0);
    acc[nt] = __builtin_amdgcn_mfma_f32_16x16x32_bf16(a2, wf[(2 * 8 + nt) * 64 + lane], acc[nt], 0, 0, 0);
    acc[nt] = __builtin_amdgcn_mfma_f32_16x16x32_bf16(a3, wf[(3 * 8 + nt) * 64 + lane], acc[nt], 0, 0, 0);
  }
  // alpha_s / alpha_d from fp32 accumulators. acc[nt][reg] = h[r0+quad*4+reg][nt*16+m]
#pragma unroll
  for (int reg = 0; reg < 4; ++reg) {
    float s = 0.f, d = 0.f;
#pragma unroll
    for (int nt = 0; nt < 8; ++nt) {
      float v = acc[nt][reg];
      s += v * asrc[nt * 16 + m];
      d += v * adst[nt * 16 + m];
    }
#pragma unroll
    for (int off = 1; off < 16; off <<= 1) { s += __shfl_xor(s, off); d += __shfl_xor(d, off); }
    if (m == 0) { as[r0 + quad * 4 + reg] = s; ad[r0 + quad * 4 + reg] = d; }
  }
  // repack to bf16 via per-wave LDS tile, then coalesced 16B stores
  unsigned short* tw = tile[wave];
#pragma unroll
  for (int nt = 0; nt < 8; ++nt)
#pragma unroll
    for (int reg = 0; reg < 4; ++reg)
      tw[(quad * 4 + reg) * 128 + nt * 16 + m] = f2bf(acc[nt][reg]);
  asm volatile("s_waitcnt lgkmcnt(0)" ::: "memory");   // wave-local LDS RAW
  const short8* tr = (const short8*)tw;
  short8* dstp = (short8*)(h1 + (size_t)r0 * 128);
#pragma unroll
  for (int sweep = 0; sweep < 4; ++sweep)
    dstp[sweep * 64 + lane] = tr[sweep * 64 + lane];
}

// ---------------- GEMM layer2: h2[N,64](bf16) = o1(bf16) @ W2, + alpha dots ----------------
__global__ __launch_bounds__(256) void k_gemm2(const unsigned short* __restrict__ o1,
                                               const unsigned short* __restrict__ Wf,
                                               const float* __restrict__ asrc,
                                               const float* __restrict__ adst,
                                               unsigned short* __restrict__ h2,
                                               float* __restrict__ as, float* __restrict__ ad) {
  __shared__ unsigned short tile[4][16 * 64];    // 8 KB
  int wave = threadIdx.x >> 6, lane = threadIdx.x & 63;
  int strip = blockIdx.x * 4 + wave;
  if (strip >= kN / 16) return;
  int r0 = strip * 16;
  int m = lane & 15, quad = lane >> 4;
  const short8* xs = (const short8*)(o1 + (size_t)(r0 + m) * 128);
  short8 a0 = xs[quad], a1 = xs[quad + 4], a2 = xs[quad + 8], a3 = xs[quad + 12];
  const short8* wf = (const short8*)Wf;
  floatx4 acc[4];
#pragma unroll
  for (int nt = 0; nt < 4; ++nt) acc[nt] = floatx4{0.f, 0.f, 0.f, 0.f};
#pragma unroll
  for (int nt = 0; nt < 4; ++nt) {
    acc[nt] = __builtin_amdgcn_mfma_f32_16x16x32_bf16(a0, wf[(0 * 4 + nt) * 64 + lane], acc[nt], 0, 0, 0);
    acc[nt] = __builtin_amdgcn_mfma_f32_16x16x32_bf16(a1, wf[(1 * 4 + nt) * 64 + lane], acc[nt], 0, 0, 0);
    acc[nt] = __builtin_amdgcn_mfma_f32_16x16x32_bf16(a2, wf[(2 * 4 + nt) * 64 + lane], acc[nt], 0, 0, 0);
    acc[nt] = __builtin_amdgcn_mfma_f32_16x16x32_bf16(a3, wf[(3 * 4 + nt) * 64 + lane], acc[nt], 0, 0, 0);
  }
#pragma unroll
  for (int reg = 0; reg < 4; ++reg) {
    float s = 0.f, d = 0.f;
#pragma unroll
    for (int nt = 0; nt < 4; ++nt) {
      float v = acc[nt][reg];
      s += v * asrc[nt * 16 + m];
      d += v * adst[nt * 16 + m];
    }
#pragma unroll
    for (int off = 1; off < 16; off <<= 1) { s += __shfl_xor(s, off); d += __shfl_xor(d, off); }
    if (m == 0) { as[r0 + quad * 4 + reg] = s; ad[r0 + quad * 4 + reg] = d; }
  }
  unsigned short* tw = tile[wave];
#pragma unroll
  for (int nt = 0; nt < 4; ++nt)
#pragma unroll
    for (int reg = 0; reg < 4; ++reg)
      tw[(quad * 4 + reg) * 64 + nt * 16 + m] = f2bf(acc[nt][reg]);
  asm volatile("s_waitcnt lgkmcnt(0)" ::: "memory");
  const short8* tr = (const short8*)tw;
  short8* dstp = (short8*)(h2 + (size_t)r0 * 64);
#pragma unroll
  for (int sweep = 0; sweep < 2; ++sweep)
    dstp[sweep * 64 + lane] = tr[sweep * 64 + lane];
}

// ---------------- aggregation: one wave per dst node, online softmax ----------------
template <int F>
__global__ __launch_bounds__(256) void k_agg(const unsigned short* __restrict__ h,
                                             const int* __restrict__ row_start,
                                             const int* __restrict__ col,
                                             const float* __restrict__ as,
                                             const float* __restrict__ ad,
                                             const float* __restrict__ bias,
                                             unsigned short* __restrict__ out) {
  int wave = threadIdx.x >> 6, lane = threadIdx.x & 63;
  int n = blockIdx.x * 4 + wave;
  if (n >= kN) return;
  int beg = row_start[n], end = row_start[n + 1];
  float adn = ad[n];
  float mrun = -1e30f, l = 0.f;
  float acc0 = 0.f, acc1 = 0.f;
  for (int j = beg; j < end; ++j) {
    int s = col[j];
    float e = as[s] + adn;
    e = e > 0.f ? e : kSlope * e;              // leaky_relu
    float nm = fmaxf(mrun, e);
    float c = __expf(mrun - nm);
    float w = __expf(e - nm);
    mrun = nm;
    l = l * c + w;
    if (F == 128) {
      unsigned int v = ((const unsigned int*)(h + (size_t)s * 128))[lane];
      acc0 = acc0 * c + w * bf2f((unsigned short)(v & 0xffffu));
      acc1 = acc1 * c + w * bf2f((unsigned short)(v >> 16));
    } else {
      float v = bf2f(h[(size_t)s * 64 + lane]);
      acc0 = acc0 * c + w * v;
    }
  }
  float invl = 1.f / l;                        // >=1 edge guaranteed (self-loop)
  if (F == 128) {
    float o0 = fmaxf(acc0 * invl + bias[2 * lane], 0.f);
    float o1 = fmaxf(acc1 * invl + bias[2 * lane + 1], 0.f);
    unsigned int packed = ((unsigned int)f2bf(o1) << 16) | f2bf(o0);
    ((unsigned int*)(out + (size_t)n * 128))[lane] = packed;
  } else {
    float o = fmaxf(acc0 * invl + bias[lane], 0.f);
    out[(size_t)n * 64 + lane] = f2bf(o);
  }
}

// ---------------- FC head: per masked row, fused fc1(relu)+fc2, fp32 out ----------------
__global__ __launch_bounds__(128) void k_fc(const unsigned short* __restrict__ o2,
                                            const int* __restrict__ mask,
                                            const float* __restrict__ fc1w,
                                            const float* __restrict__ fc1b,
                                            const float* __restrict__ fc2w,
                                            const float* __restrict__ fc2b,
                                            float* __restrict__ out) {
  __shared__ float hm[64];
  __shared__ float z[128];
  int b = blockIdx.x, t = threadIdx.x;
  int row = mask[b];
  if (t < 64) hm[t] = bf2f(o2[(size_t)row * 64 + t]);
  __syncthreads();
  float a = fc1b[t];
#pragma unroll 8
  for (int k = 0; k < 64; ++k) a += hm[k] * fc1w[k * 128 + t];
  z[t] = fmaxf(a, 0.f);
  __syncthreads();
  if (t < 10) {
    float o = fc2b[t];
#pragma unroll 8
    for (int k = 0; k < 128; ++k) o += z[k] * fc2w[k * 10 + t];
    out[(size_t)b * 10 + t] = o;
  }
}

extern "C" void kernel_launch(void* const* d_in, const int* in_sizes, int n_in,
                              void* d_out, int out_size, void* d_ws, size_t ws_size,
                              hipStream_t stream) {
  const float* x     = (const float*)d_in[0];
  const int*   ei    = (const int*)d_in[1];     // [2,E] as int32 (harness converts)
  const int*   mask  = (const int*)d_in[2];
  const float* W1    = (const float*)d_in[3];
  const float* asrc1 = (const float*)d_in[4];
  const float* adst1 = (const float*)d_in[5];
  const float* b1    = (const float*)d_in[6];
  const float* W2    = (const float*)d_in[7];
  const float* asrc2 = (const float*)d_in[8];
  const float* adst2 = (const float*)d_in[9];
  const float* b2    = (const float*)d_in[10];
  const float* fc1w  = (const float*)d_in[11];
  const float* fc1b  = (const float*)d_in[12];
  const float* fc2w  = (const float*)d_in[13];
  const float* fc2b  = (const float*)d_in[14];
  float* out = (float*)d_out;

  const int* esrc = ei;
  const int* edst = ei + kE;

  // -------- workspace layout (small arrays first; total ~61 MB) --------
  char* ws = (char*)d_ws;
  size_t off = 0;
  auto alloc = [&](size_t bytes) -> void* {
    void* p = ws + off;
    off = (off + bytes + 255) & ~(size_t)255;
    return p;
  };
  unsigned short* Wf1    = (unsigned short*)alloc(128 * 128 * 2);       // 32 KB
  unsigned short* Wf2    = (unsigned short*)alloc(128 * 64 * 2);        // 16 KB
  int*            rstart = (int*)alloc((size_t)(kN + 1) * 4);           // 0.4 MB
  int*            counts = (int*)alloc((size_t)kN * 4);                 // 0.4 MB (doubles as cursor)
  float*          as1    = (float*)alloc((size_t)kN * 4);
  float*          ad1    = (float*)alloc((size_t)kN * 4);
  float*          as2    = (float*)alloc((size_t)kN * 4);
  float*          ad2    = (float*)alloc((size_t)kN * 4);               // 1.6 MB total
  int*            colidx = (int*)alloc((size_t)kTotE * 4);              // 6.8 MB
  unsigned short* h1     = (unsigned short*)alloc((size_t)kN * 128 * 2);// 25.6 MB
  unsigned short* o1     = (unsigned short*)alloc((size_t)kN * 128 * 2);// 25.6 MB
  // h2/o2 alias the h1 region (h1 dead after k_agg<128>)
  unsigned short* h2 = h1;                       // 12.8 MB
  unsigned short* o2 = h1 + (size_t)kN * 64;     // 12.8 MB
  int* cursor = counts;
  (void)ws_size; (void)in_sizes; (void)n_in; (void)out_size;

  // CSR build (ws re-poisoned every call -> rebuild each time)
  k_init_counts<<<(kN + 255) / 256, 256, 0, stream>>>(counts);
  k_count<<<(kE + 255) / 256, 256, 0, stream>>>(edst, counts);
  k_scan<<<1, 1024, 0, stream>>>(counts, rstart, cursor);
  k_fill<<<(kTotE + 255) / 256, 256, 0, stream>>>(esrc, edst, cursor, colidx);

  // Weight swizzle (fp32 -> bf16) for MFMA B-frags
  k_wprep<<<(128 * 128 + 255) / 256, 256, 0, stream>>>(W1, Wf1, 128, 128);
  k_wprep<<<(128 * 64 + 255) / 256, 256, 0, stream>>>(W2, Wf2, 128, 64);

  const int gemmBlocks = (kN / 16 + 3) / 4;   // 6250 strips, 4 waves/block
  const int nodeBlocks = (kN + 3) / 4;        // 1 wave per node

  // Layer 1
  k_gemm1<<<gemmBlocks, 256, 0, stream>>>(x, Wf1, asrc1, adst1, h1, as1, ad1);
  k_agg<128><<<nodeBlocks, 256, 0, stream>>>(h1, rstart, colidx, as1, ad1, b1, o1);
  // Layer 2 (h2/o2 live in the dead h1 region)
  k_gemm2<<<gemmBlocks, 256, 0, stream>>>(o1, Wf2, asrc2, adst2, h2, as2, ad2);
  k_agg<64><<<nodeBlocks, 256, 0, stream>>>(h2, rstart, colidx, as2, ad2, b2, o2);
  // FC head
  k_fc<<<kM, 128, 0, stream>>>(o2, mask, fc1w, fc1b, fc2w, fc2b, out);
}

// Round 4
// 709.190 us; speedup vs baseline: 1.4488x; 1.4488x over previous
//
#include <hip/hip_runtime.h>

constexpr int kN    = 100000;   // nodes
constexpr int kE    = 1600000;  // random edges
constexpr int kTotE = kE + kN;  // + self loops
constexpr int kM    = 20000;    // masked rows
constexpr float kSlope = 0.2f;

constexpr int kScanTile   = 1024;                          // elems per scan block
constexpr int kScanBlocks = (kN + kScanTile - 1) / kScanTile;  // 98

typedef short short8  __attribute__((ext_vector_type(8)));
typedef float floatx4 __attribute__((ext_vector_type(4)));

__device__ __forceinline__ float bf2f(unsigned short u) {
  union { unsigned int i; float f; } v; v.i = ((unsigned int)u) << 16; return v.f;
}
__device__ __forceinline__ unsigned short f2bf(float f) {
  union { float f; unsigned int i; } v; v.f = f;
  unsigned int x = v.i;
  x += 0x7fffu + ((x >> 16) & 1u);   // RNE
  return (unsigned short)(x >> 16);
}
__device__ __forceinline__ short8 pack8(float4 u, float4 v) {
  short8 r;
  r[0] = (short)f2bf(u.x); r[1] = (short)f2bf(u.y);
  r[2] = (short)f2bf(u.z); r[3] = (short)f2bf(u.w);
  r[4] = (short)f2bf(v.x); r[5] = (short)f2bf(v.y);
  r[6] = (short)f2bf(v.z); r[7] = (short)f2bf(v.w);
  return r;
}

// ---------------- CSR build ----------------
__global__ void k_init_counts(int* counts) {
  int i = blockIdx.x * 256 + threadIdx.x;
  if (i < kN) counts[i] = 1;              // self-loop
}

__global__ void k_count(const int* __restrict__ dst, int* __restrict__ counts) {
  int i = blockIdx.x * 256 + threadIdx.x;
  if (i < kE) atomicAdd(&counts[dst[i]], 1);
}

// ---- scan phase A: per-block sums (1024 elems / block of 256) ----
__global__ __launch_bounds__(256) void k_scan_part(const int* __restrict__ counts,
                                                   int* __restrict__ bsum) {
  int b = blockIdx.x, t = threadIdx.x;
  int i0 = b * kScanTile + t * 4;
  int s = 0;
  if (i0 + 3 < kN) {
    int4 v = *(const int4*)(counts + i0);
    s = v.x + v.y + v.z + v.w;
  } else {
    for (int k = 0; k < 4; ++k) if (i0 + k < kN) s += counts[i0 + k];
  }
  for (int off = 32; off; off >>= 1) s += __shfl_down(s, off);
  __shared__ int wsum[4];
  int wave = t >> 6, lane = t & 63;
  if (lane == 0) wsum[wave] = s;
  __syncthreads();
  if (t == 0) bsum[b] = wsum[0] + wsum[1] + wsum[2] + wsum[3];
}

// ---- scan phase B: single tiny block scans the 98 block sums -> exclusive offsets ----
__global__ __launch_bounds__(128) void k_scan_bsum(int* bsum, int* row_start) {
  __shared__ int sh[128];
  int t = threadIdx.x;
  int v = (t < kScanBlocks) ? bsum[t] : 0;
  sh[t] = v;
  __syncthreads();
  for (int off = 1; off < 128; off <<= 1) {
    int u = (t >= off) ? sh[t - off] : 0;
    __syncthreads();
    sh[t] += u;
    __syncthreads();
  }
  if (t < kScanBlocks) bsum[t] = (t == 0) ? 0 : sh[t - 1];
  if (t == 127) row_start[kN] = sh[127];   // grand total = kTotE
}

// ---- scan phase C: block-local exclusive scan + global offset; writes row_start & cursor ----
__global__ __launch_bounds__(256) void k_scan_write(const int* __restrict__ counts,
                                                    const int* __restrict__ bsum,
                                                    int* __restrict__ row_start,
                                                    int* __restrict__ cursor) {
  int b = blockIdx.x, t = threadIdx.x;
  int wave = t >> 6, lane = t & 63;
  int i0 = b * kScanTile + t * 4;
  int v0 = 0, v1 = 0, v2 = 0, v3 = 0;
  if (i0 + 3 < kN) {
    int4 v = *(const int4*)(counts + i0);
    v0 = v.x; v1 = v.y; v2 = v.z; v3 = v.w;
  } else {
    if (i0     < kN) v0 = counts[i0];
    if (i0 + 1 < kN) v1 = counts[i0 + 1];
    if (i0 + 2 < kN) v2 = counts[i0 + 2];
    if (i0 + 3 < kN) v3 = counts[i0 + 3];
  }
  int tot = v0 + v1 + v2 + v3;
  int s = tot;
#pragma unroll
  for (int off = 1; off < 64; off <<= 1) {
    int u = __shfl_up(s, off);
    if (lane >= off) s += u;
  }
  __shared__ int wsum[4];
  if (lane == 63) wsum[wave] = s;
  __syncthreads();
  int woff = 0;
  for (int w = 0; w < wave; ++w) woff += wsum[w];
  int base = bsum[b] + woff + (s - tot);   // exclusive prefix for this thread's 4 elems
  int r0 = base, r1 = base + v0, r2 = r1 + v1, r3 = r2 + v2;
  if (i0 + 3 < kN) {
    *(int4*)(row_start + i0) = int4{r0, r1, r2, r3};
    *(int4*)(cursor + i0)    = int4{r0, r1, r2, r3};
  } else {
    if (i0     < kN) { row_start[i0]     = r0; cursor[i0]     = r0; }
    if (i0 + 1 < kN) { row_start[i0 + 1] = r1; cursor[i0 + 1] = r1; }
    if (i0 + 2 < kN) { row_start[i0 + 2] = r2; cursor[i0 + 2] = r2; }
    if (i0 + 3 < kN) { row_start[i0 + 3] = r3; cursor[i0 + 3] = r3; }
  }
}

__global__ void k_fill(const int* __restrict__ src, const int* __restrict__ dst,
                       int* __restrict__ cursor, int* __restrict__ col) {
  int i = blockIdx.x * 256 + threadIdx.x;
  if (i >= kTotE) return;
  int s, d;
  if (i < kE) { s = src[i]; d = dst[i]; }
  else        { s = d = i - kE; }
  int pos = atomicAdd(&cursor[d], 1);
  col[pos] = s;
}

// ---------------- weight pre-swizzle (fp32 -> bf16) into MFMA B-frag order ----------------
__global__ void k_wprep(const float* __restrict__ W,
                        unsigned short* __restrict__ Wf, int K, int Fo) {
  int idx = blockIdx.x * 256 + threadIdx.x;
  if (idx >= K * Fo) return;
  int j    = idx & 7;
  int lane = (idx >> 3) & 63;
  int t    = idx >> 9;
  int NT = Fo >> 4;
  int kt = t / NT, nt = t - kt * NT;
  int k = kt * 32 + ((lane >> 4) & 3) * 8 + j;
  int n = nt * 16 + (lane & 15);
  Wf[idx] = f2bf(W[k * Fo + n]);
}

// ---------------- GEMM layer1: h1[N,128](bf16) = x(fp32) @ W1, + alpha dots (fp32) ----------------
__global__ __launch_bounds__(256) void k_gemm1(const float* __restrict__ x,
                                               const unsigned short* __restrict__ Wf,
                                               const float* __restrict__ asrc,
                                               const float* __restrict__ adst,
                                               unsigned short* __restrict__ h1,
                                               float* __restrict__ as, float* __restrict__ ad) {
  __shared__ unsigned short tile[4][16 * 128];   // 16 KB, per-wave regions
  int wave = threadIdx.x >> 6, lane = threadIdx.x & 63;
  int strip = blockIdx.x * 4 + wave;
  if (strip >= kN / 16) return;
  int r0 = strip * 16;
  int m = lane & 15, quad = lane >> 4;
  const float4* xf = (const float4*)(x + (size_t)(r0 + m) * 128);   // 32 float4 per row
  short8 a0 = pack8(xf[quad * 2 + 0],  xf[quad * 2 + 1]);           // k-tile 0
  short8 a1 = pack8(xf[quad * 2 + 8],  xf[quad * 2 + 9]);           // k-tile 1
  short8 a2 = pack8(xf[quad * 2 + 16], xf[quad * 2 + 17]);          // k-tile 2
  short8 a3 = pack8(xf[quad * 2 + 24], xf[quad * 2 + 25]);          // k-tile 3
  const short8* wf = (const short8*)Wf;
  floatx4 acc[8];
#pragma unroll
  for (int nt = 0; nt < 8; ++nt) acc[nt] = floatx4{0.f, 0.f, 0.f, 0.f};
#pragma unroll
  for (int nt = 0; nt < 8; ++nt) {
    acc[nt] = __builtin_amdgcn_mfma_f32_16x16x32_bf16(a0, wf[(0 * 8 + nt) * 64 + lane], acc[nt], 0, 0, 0);
    acc[nt] = __builtin_amdgcn_mfma_f32_16x16x32_bf16(a1, wf[(1 * 8 + nt) * 64 + lane], acc[nt], 0, 0, 0);
    acc[nt] = __builtin_amdgcn_mfma_f32_16x16x32_bf16(a2, wf[(2 * 8 + nt) * 64 + lane], acc[nt], 0, 0, 0);
    acc[nt] = __builtin_amdgcn_mfma_f32_16x16x32_bf16(a3, wf[(3 * 8 + nt) * 64 + lane], acc[nt], 0, 0, 0);
  }
  // alpha_s / alpha_d from fp32 accumulators. acc[nt][reg] = h[r0+quad*4+reg][nt*16+m]
#pragma unroll
  for (int reg = 0; reg < 4; ++reg) {
    float s = 0.f, d = 0.f;
#pragma unroll
    for (int nt = 0; nt < 8; ++nt) {
      float v = acc[nt][reg];
      s += v * asrc[nt * 16 + m];
      d += v * adst[nt * 16 + m];
    }
#pragma unroll
    for (int off = 1; off < 16; off <<= 1) { s += __shfl_xor(s, off); d += __shfl_xor(d, off); }
    if (m == 0) { as[r0 + quad * 4 + reg] = s; ad[r0 + quad * 4 + reg] = d; }
  }
  // repack to bf16 via per-wave LDS tile, then coalesced 16B stores
  unsigned short* tw = tile[wave];
#pragma unroll
  for (int nt = 0; nt < 8; ++nt)
#pragma unroll
    for (int reg = 0; reg < 4; ++reg)
      tw[(quad * 4 + reg) * 128 + nt * 16 + m] = f2bf(acc[nt][reg]);
  asm volatile("s_waitcnt lgkmcnt(0)" ::: "memory");   // wave-local LDS RAW
  const short8* tr = (const short8*)tw;
  short8* dstp = (short8*)(h1 + (size_t)r0 * 128);
#pragma unroll
  for (int sweep = 0; sweep < 4; ++sweep)
    dstp[sweep * 64 + lane] = tr[sweep * 64 + lane];
}

// ---------------- GEMM layer2: h2[N,64](bf16) = o1(bf16) @ W2, + alpha dots ----------------
__global__ __launch_bounds__(256) void k_gemm2(const unsigned short* __restrict__ o1,
                                               const unsigned short* __restrict__ Wf,
                                               const float* __restrict__ asrc,
                                               const float* __restrict__ adst,
                                               unsigned short* __restrict__ h2,
                                               float* __restrict__ as, float* __restrict__ ad) {
  __shared__ unsigned short tile[4][16 * 64];    // 8 KB
  int wave = threadIdx.x >> 6, lane = threadIdx.x & 63;
  int strip = blockIdx.x * 4 + wave;
  if (strip >= kN / 16) return;
  int r0 = strip * 16;
  int m = lane & 15, quad = lane >> 4;
  const short8* xs = (const short8*)(o1 + (size_t)(r0 + m) * 128);
  short8 a0 = xs[quad], a1 = xs[quad + 4], a2 = xs[quad + 8], a3 = xs[quad + 12];
  const short8* wf = (const short8*)Wf;
  floatx4 acc[4];
#pragma unroll
  for (int nt = 0; nt < 4; ++nt) acc[nt] = floatx4{0.f, 0.f, 0.f, 0.f};
#pragma unroll
  for (int nt = 0; nt < 4; ++nt) {
    acc[nt] = __builtin_amdgcn_mfma_f32_16x16x32_bf16(a0, wf[(0 * 4 + nt) * 64 + lane], acc[nt], 0, 0, 0);
    acc[nt] = __builtin_amdgcn_mfma_f32_16x16x32_bf16(a1, wf[(1 * 4 + nt) * 64 + lane], acc[nt], 0, 0, 0);
    acc[nt] = __builtin_amdgcn_mfma_f32_16x16x32_bf16(a2, wf[(2 * 4 + nt) * 64 + lane], acc[nt], 0, 0, 0);
    acc[nt] = __builtin_amdgcn_mfma_f32_16x16x32_bf16(a3, wf[(3 * 4 + nt) * 64 + lane], acc[nt], 0, 0, 0);
  }
#pragma unroll
  for (int reg = 0; reg < 4; ++reg) {
    float s = 0.f, d = 0.f;
#pragma unroll
    for (int nt = 0; nt < 4; ++nt) {
      float v = acc[nt][reg];
      s += v * asrc[nt * 16 + m];
      d += v * adst[nt * 16 + m];
    }
#pragma unroll
    for (int off = 1; off < 16; off <<= 1) { s += __shfl_xor(s, off); d += __shfl_xor(d, off); }
    if (m == 0) { as[r0 + quad * 4 + reg] = s; ad[r0 + quad * 4 + reg] = d; }
  }
  unsigned short* tw = tile[wave];
#pragma unroll
  for (int nt = 0; nt < 4; ++nt)
#pragma unroll
    for (int reg = 0; reg < 4; ++reg)
      tw[(quad * 4 + reg) * 64 + nt * 16 + m] = f2bf(acc[nt][reg]);
  asm volatile("s_waitcnt lgkmcnt(0)" ::: "memory");
  const short8* tr = (const short8*)tw;
  short8* dstp = (short8*)(h2 + (size_t)r0 * 64);
#pragma unroll
  for (int sweep = 0; sweep < 2; ++sweep)
    dstp[sweep * 64 + lane] = tr[sweep * 64 + lane];
}

// ---------------- aggregation: one wave per dst node, online softmax ----------------
template <int F>
__global__ __launch_bounds__(256) void k_agg(const unsigned short* __restrict__ h,
                                             const int* __restrict__ row_start,
                                             const int* __restrict__ col,
                                             const float* __restrict__ as,
                                             const float* __restrict__ ad,
                                             const float* __restrict__ bias,
                                             unsigned short* __restrict__ out) {
  int wave = threadIdx.x >> 6, lane = threadIdx.x & 63;
  int n = blockIdx.x * 4 + wave;
  if (n >= kN) return;
  int beg = row_start[n], end = row_start[n + 1];
  float adn = ad[n];
  float mrun = -1e30f, l = 0.f;
  float acc0 = 0.f, acc1 = 0.f;
  for (int j = beg; j < end; ++j) {
    int s = col[j];
    float e = as[s] + adn;
    e = e > 0.f ? e : kSlope * e;              // leaky_relu
    float nm = fmaxf(mrun, e);
    float c = __expf(mrun - nm);
    float w = __expf(e - nm);
    mrun = nm;
    l = l * c + w;
    if (F == 128) {
      unsigned int v = ((const unsigned int*)(h + (size_t)s * 128))[lane];
      acc0 = acc0 * c + w * bf2f((unsigned short)(v & 0xffffu));
      acc1 = acc1 * c + w * bf2f((unsigned short)(v >> 16));
    } else {
      float v = bf2f(h[(size_t)s * 64 + lane]);
      acc0 = acc0 * c + w * v;
    }
  }
  float invl = 1.f / l;                        // >=1 edge guaranteed (self-loop)
  if (F == 128) {
    float o0 = fmaxf(acc0 * invl + bias[2 * lane], 0.f);
    float o1 = fmaxf(acc1 * invl + bias[2 * lane + 1], 0.f);
    unsigned int packed = ((unsigned int)f2bf(o1) << 16) | f2bf(o0);
    ((unsigned int*)(out + (size_t)n * 128))[lane] = packed;
  } else {
    float o = fmaxf(acc0 * invl + bias[lane], 0.f);
    out[(size_t)n * 64 + lane] = f2bf(o);
  }
}

// ---------------- FC head: per masked row, fused fc1(relu)+fc2, fp32 out ----------------
__global__ __launch_bounds__(128) void k_fc(const unsigned short* __restrict__ o2,
                                            const int* __restrict__ mask,
                                            const float* __restrict__ fc1w,
                                            const float* __restrict__ fc1b,
                                            const float* __restrict__ fc2w,
                                            const float* __restrict__ fc2b,
                                            float* __restrict__ out) {
  __shared__ float hm[64];
  __shared__ float z[128];
  int b = blockIdx.x, t = threadIdx.x;
  int row = mask[b];
  if (t < 64) hm[t] = bf2f(o2[(size_t)row * 64 + t]);
  __syncthreads();
  float a = fc1b[t];
#pragma unroll 8
  for (int k = 0; k < 64; ++k) a += hm[k] * fc1w[k * 128 + t];
  z[t] = fmaxf(a, 0.f);
  __syncthreads();
  if (t < 10) {
    float o = fc2b[t];
#pragma unroll 8
    for (int k = 0; k < 128; ++k) o += z[k] * fc2w[k * 10 + t];
    out[(size_t)b * 10 + t] = o;
  }
}

extern "C" void kernel_launch(void* const* d_in, const int* in_sizes, int n_in,
                              void* d_out, int out_size, void* d_ws, size_t ws_size,
                              hipStream_t stream) {
  const float* x     = (const float*)d_in[0];
  const int*   ei    = (const int*)d_in[1];     // [2,E] as int32 (harness converts)
  const int*   mask  = (const int*)d_in[2];
  const float* W1    = (const float*)d_in[3];
  const float* asrc1 = (const float*)d_in[4];
  const float* adst1 = (const float*)d_in[5];
  const float* b1    = (const float*)d_in[6];
  const float* W2    = (const float*)d_in[7];
  const float* asrc2 = (const float*)d_in[8];
  const float* adst2 = (const float*)d_in[9];
  const float* b2    = (const float*)d_in[10];
  const float* fc1w  = (const float*)d_in[11];
  const float* fc1b  = (const float*)d_in[12];
  const float* fc2w  = (const float*)d_in[13];
  const float* fc2b  = (const float*)d_in[14];
  float* out = (float*)d_out;

  const int* esrc = ei;
  const int* edst = ei + kE;

  // -------- workspace layout (small arrays first; total ~62 MB) --------
  char* ws = (char*)d_ws;
  size_t off = 0;
  auto alloc = [&](size_t bytes) -> void* {
    void* p = ws + off;
    off = (off + bytes + 255) & ~(size_t)255;
    return p;
  };
  unsigned short* Wf1    = (unsigned short*)alloc(128 * 128 * 2);       // 32 KB
  unsigned short* Wf2    = (unsigned short*)alloc(128 * 64 * 2);        // 16 KB
  int*            rstart = (int*)alloc((size_t)(kN + 1) * 4);           // 0.4 MB
  int*            counts = (int*)alloc((size_t)kN * 4);                 // 0.4 MB
  int*            cursor = (int*)alloc((size_t)kN * 4);                 // 0.4 MB
  int*            bsum   = (int*)alloc((size_t)kScanBlocks * 4);        // tiny
  float*          as1    = (float*)alloc((size_t)kN * 4);
  float*          ad1    = (float*)alloc((size_t)kN * 4);
  float*          as2    = (float*)alloc((size_t)kN * 4);
  float*          ad2    = (float*)alloc((size_t)kN * 4);               // 1.6 MB total
  int*            colidx = (int*)alloc((size_t)kTotE * 4);              // 6.8 MB
  unsigned short* h1     = (unsigned short*)alloc((size_t)kN * 128 * 2);// 25.6 MB
  unsigned short* o1     = (unsigned short*)alloc((size_t)kN * 128 * 2);// 25.6 MB
  // h2/o2 alias the h1 region (h1 dead after k_agg<128>)
  unsigned short* h2 = h1;                       // 12.8 MB
  unsigned short* o2 = h1 + (size_t)kN * 64;     // 12.8 MB
  (void)ws_size; (void)in_sizes; (void)n_in; (void)out_size;

  // CSR build (ws re-poisoned every call -> rebuild each time)
  k_init_counts<<<(kN + 255) / 256, 256, 0, stream>>>(counts);
  k_count<<<(kE + 255) / 256, 256, 0, stream>>>(edst, counts);
  k_scan_part<<<kScanBlocks, 256, 0, stream>>>(counts, bsum);
  k_scan_bsum<<<1, 128, 0, stream>>>(bsum, rstart);
  k_scan_write<<<kScanBlocks, 256, 0, stream>>>(counts, bsum, rstart, cursor);
  k_fill<<<(kTotE + 255) / 256, 256, 0, stream>>>(esrc, edst, cursor, colidx);

  // Weight swizzle (fp32 -> bf16) for MFMA B-frags
  k_wprep<<<(128 * 128 + 255) / 256, 256, 0, stream>>>(W1, Wf1, 128, 128);
  k_wprep<<<(128 * 64 + 255) / 256, 256, 0, stream>>>(W2, Wf2, 128, 64);

  const int gemmBlocks = (kN / 16 + 3) / 4;   // 6250 strips, 4 waves/block
  const int nodeBlocks = (kN + 3) / 4;        // 1 wave per node

  // Layer 1
  k_gemm1<<<gemmBlocks, 256, 0, stream>>>(x, Wf1, asrc1, adst1, h1, as1, ad1);
  k_agg<128><<<nodeBlocks, 256, 0, stream>>>(h1, rstart, colidx, as1, ad1, b1, o1);
  // Layer 2 (h2/o2 live in the dead h1 region)
  k_gemm2<<<gemmBlocks, 256, 0, stream>>>(o1, Wf2, asrc2, adst2, h2, as2, ad2);
  k_agg<64><<<nodeBlocks, 256, 0, stream>>>(h2, rstart, colidx, as2, ad2, b2, o2);
  // FC head
  k_fc<<<kM, 128, 0, stream>>>(o2, mask, fc1w, fc1b, fc2w, fc2b, out);
}

// Round 5
// 564.572 us; speedup vs baseline: 1.8199x; 1.2562x over previous
//
#include <hip/hip_runtime.h>

constexpr int kN    = 100000;   // nodes
constexpr int kE    = 1600000;  // random edges
constexpr int kTotE = kE + kN;  // + self loops
constexpr int kM    = 20000;    // masked rows
constexpr float kSlope = 0.2f;

constexpr int kScanTile   = 1024;                          // elems per scan block
constexpr int kScanBlocks = (kN + kScanTile - 1) / kScanTile;  // 98

typedef short short8  __attribute__((ext_vector_type(8)));
typedef float floatx4 __attribute__((ext_vector_type(4)));

__device__ __forceinline__ float bf2f(unsigned short u) {
  union { unsigned int i; float f; } v; v.i = ((unsigned int)u) << 16; return v.f;
}
__device__ __forceinline__ unsigned short f2bf(float f) {
  union { float f; unsigned int i; } v; v.f = f;
  unsigned int x = v.i;
  x += 0x7fffu + ((x >> 16) & 1u);   // RNE
  return (unsigned short)(x >> 16);
}
__device__ __forceinline__ short8 pack8(float4 u, float4 v) {
  short8 r;
  r[0] = (short)f2bf(u.x); r[1] = (short)f2bf(u.y);
  r[2] = (short)f2bf(u.z); r[3] = (short)f2bf(u.w);
  r[4] = (short)f2bf(v.x); r[5] = (short)f2bf(v.y);
  r[6] = (short)f2bf(v.z); r[7] = (short)f2bf(v.w);
  return r;
}

// ---------------- CSR build ----------------
__global__ void k_init_counts(int* counts) {
  int i = blockIdx.x * 256 + threadIdx.x;
  if (i < kN) counts[i] = 1;              // self-loop
}

__global__ void k_count(const int* __restrict__ dst, int* __restrict__ counts) {
  int i = blockIdx.x * 256 + threadIdx.x;
  if (i < kE) atomicAdd(&counts[dst[i]], 1);
}

// ---- scan phase A: per-block sums (1024 elems / block of 256) ----
__global__ __launch_bounds__(256) void k_scan_part(const int* __restrict__ counts,
                                                   int* __restrict__ bsum) {
  int b = blockIdx.x, t = threadIdx.x;
  int i0 = b * kScanTile + t * 4;
  int s = 0;
  if (i0 + 3 < kN) {
    int4 v = *(const int4*)(counts + i0);
    s = v.x + v.y + v.z + v.w;
  } else {
    for (int k = 0; k < 4; ++k) if (i0 + k < kN) s += counts[i0 + k];
  }
  for (int off = 32; off; off >>= 1) s += __shfl_down(s, off);
  __shared__ int wsum[4];
  int wave = t >> 6, lane = t & 63;
  if (lane == 0) wsum[wave] = s;
  __syncthreads();
  if (t == 0) bsum[b] = wsum[0] + wsum[1] + wsum[2] + wsum[3];
}

// ---- scan phase B: single tiny block scans the 98 block sums -> exclusive offsets ----
__global__ __launch_bounds__(128) void k_scan_bsum(int* bsum, int* row_start) {
  __shared__ int sh[128];
  int t = threadIdx.x;
  int v = (t < kScanBlocks) ? bsum[t] : 0;
  sh[t] = v;
  __syncthreads();
  for (int off = 1; off < 128; off <<= 1) {
    int u = (t >= off) ? sh[t - off] : 0;
    __syncthreads();
    sh[t] += u;
    __syncthreads();
  }
  if (t < kScanBlocks) bsum[t] = (t == 0) ? 0 : sh[t - 1];
  if (t == 127) row_start[kN] = sh[127];   // grand total = kTotE
}

// ---- scan phase C: block-local exclusive scan + global offset; writes row_start & cursor ----
__global__ __launch_bounds__(256) void k_scan_write(const int* __restrict__ counts,
                                                    const int* __restrict__ bsum,
                                                    int* __restrict__ row_start,
                                                    int* __restrict__ cursor) {
  int b = blockIdx.x, t = threadIdx.x;
  int wave = t >> 6, lane = t & 63;
  int i0 = b * kScanTile + t * 4;
  int v0 = 0, v1 = 0, v2 = 0, v3 = 0;
  if (i0 + 3 < kN) {
    int4 v = *(const int4*)(counts + i0);
    v0 = v.x; v1 = v.y; v2 = v.z; v3 = v.w;
  } else {
    if (i0     < kN) v0 = counts[i0];
    if (i0 + 1 < kN) v1 = counts[i0 + 1];
    if (i0 + 2 < kN) v2 = counts[i0 + 2];
    if (i0 + 3 < kN) v3 = counts[i0 + 3];
  }
  int tot = v0 + v1 + v2 + v3;
  int s = tot;
#pragma unroll
  for (int off = 1; off < 64; off <<= 1) {
    int u = __shfl_up(s, off);
    if (lane >= off) s += u;
  }
  __shared__ int wsum[4];
  if (lane == 63) wsum[wave] = s;
  __syncthreads();
  int woff = 0;
  for (int w = 0; w < wave; ++w) woff += wsum[w];
  int base = bsum[b] + woff + (s - tot);   // exclusive prefix for this thread's 4 elems
  int r0 = base, r1 = base + v0, r2 = r1 + v1, r3 = r2 + v2;
  if (i0 + 3 < kN) {
    *(int4*)(row_start + i0) = int4{r0, r1, r2, r3};
    *(int4*)(cursor + i0)    = int4{r0, r1, r2, r3};
  } else {
    if (i0     < kN) { row_start[i0]     = r0; cursor[i0]     = r0; }
    if (i0 + 1 < kN) { row_start[i0 + 1] = r1; cursor[i0 + 1] = r1; }
    if (i0 + 2 < kN) { row_start[i0 + 2] = r2; cursor[i0 + 2] = r2; }
    if (i0 + 3 < kN) { row_start[i0 + 3] = r3; cursor[i0 + 3] = r3; }
  }
}

__global__ void k_fill(const int* __restrict__ src, const int* __restrict__ dst,
                       int* __restrict__ cursor, int* __restrict__ col) {
  int i = blockIdx.x * 256 + threadIdx.x;
  if (i >= kTotE) return;
  int s, d;
  if (i < kE) { s = src[i]; d = dst[i]; }
  else        { s = d = i - kE; }
  int pos = atomicAdd(&cursor[d], 1);
  col[pos] = s;
}

// ---------------- weight pre-swizzle (fp32 -> bf16) into MFMA B-frag order ----------------
__global__ void k_wprep(const float* __restrict__ W,
                        unsigned short* __restrict__ Wf, int K, int Fo) {
  int idx = blockIdx.x * 256 + threadIdx.x;
  if (idx >= K * Fo) return;
  int j    = idx & 7;
  int lane = (idx >> 3) & 63;
  int t    = idx >> 9;
  int NT = Fo >> 4;
  int kt = t / NT, nt = t - kt * NT;
  int k = kt * 32 + ((lane >> 4) & 3) * 8 + j;
  int n = nt * 16 + (lane & 15);
  Wf[idx] = f2bf(W[k * Fo + n]);
}

// ---------------- GEMM layer1: h1[N,128](bf16) = x(fp32) @ W1, + alpha dots (fp32) ----------------
__global__ __launch_bounds__(256) void k_gemm1(const float* __restrict__ x,
                                               const unsigned short* __restrict__ Wf,
                                               const float* __restrict__ asrc,
                                               const float* __restrict__ adst,
                                               unsigned short* __restrict__ h1,
                                               float* __restrict__ as, float* __restrict__ ad) {
  __shared__ unsigned short tile[4][16 * 128];   // 16 KB, per-wave regions
  int wave = threadIdx.x >> 6, lane = threadIdx.x & 63;
  int strip = blockIdx.x * 4 + wave;
  if (strip >= kN / 16) return;
  int r0 = strip * 16;
  int m = lane & 15, quad = lane >> 4;
  const float4* xf = (const float4*)(x + (size_t)(r0 + m) * 128);   // 32 float4 per row
  short8 a0 = pack8(xf[quad * 2 + 0],  xf[quad * 2 + 1]);           // k-tile 0
  short8 a1 = pack8(xf[quad * 2 + 8],  xf[quad * 2 + 9]);           // k-tile 1
  short8 a2 = pack8(xf[quad * 2 + 16], xf[quad * 2 + 17]);          // k-tile 2
  short8 a3 = pack8(xf[quad * 2 + 24], xf[quad * 2 + 25]);          // k-tile 3
  const short8* wf = (const short8*)Wf;
  floatx4 acc[8];
#pragma unroll
  for (int nt = 0; nt < 8; ++nt) acc[nt] = floatx4{0.f, 0.f, 0.f, 0.f};
#pragma unroll
  for (int nt = 0; nt < 8; ++nt) {
    acc[nt] = __builtin_amdgcn_mfma_f32_16x16x32_bf16(a0, wf[(0 * 8 + nt) * 64 + lane], acc[nt], 0, 0, 0);
    acc[nt] = __builtin_amdgcn_mfma_f32_16x16x32_bf16(a1, wf[(1 * 8 + nt) * 64 + lane], acc[nt], 0, 0, 0);
    acc[nt] = __builtin_amdgcn_mfma_f32_16x16x32_bf16(a2, wf[(2 * 8 + nt) * 64 + lane], acc[nt], 0, 0, 0);
    acc[nt] = __builtin_amdgcn_mfma_f32_16x16x32_bf16(a3, wf[(3 * 8 + nt) * 64 + lane], acc[nt], 0, 0, 0);
  }
  // alpha_s / alpha_d from fp32 accumulators. acc[nt][reg] = h[r0+quad*4+reg][nt*16+m]
#pragma unroll
  for (int reg = 0; reg < 4; ++reg) {
    float s = 0.f, d = 0.f;
#pragma unroll
    for (int nt = 0; nt < 8; ++nt) {
      float v = acc[nt][reg];
      s += v * asrc[nt * 16 + m];
      d += v * adst[nt * 16 + m];
    }
#pragma unroll
    for (int off = 1; off < 16; off <<= 1) { s += __shfl_xor(s, off); d += __shfl_xor(d, off); }
    if (m == 0) { as[r0 + quad * 4 + reg] = s; ad[r0 + quad * 4 + reg] = d; }
  }
  // repack to bf16 via per-wave LDS tile, then coalesced 16B stores
  unsigned short* tw = tile[wave];
#pragma unroll
  for (int nt = 0; nt < 8; ++nt)
#pragma unroll
    for (int reg = 0; reg < 4; ++reg)
      tw[(quad * 4 + reg) * 128 + nt * 16 + m] = f2bf(acc[nt][reg]);
  asm volatile("s_waitcnt lgkmcnt(0)" ::: "memory");   // wave-local LDS RAW
  const short8* tr = (const short8*)tw;
  short8* dstp = (short8*)(h1 + (size_t)r0 * 128);
#pragma unroll
  for (int sweep = 0; sweep < 4; ++sweep)
    dstp[sweep * 64 + lane] = tr[sweep * 64 + lane];
}

// ---------------- GEMM layer2: h2[N,64](bf16) = o1(bf16) @ W2, + alpha dots ----------------
__global__ __launch_bounds__(256) void k_gemm2(const unsigned short* __restrict__ o1,
                                               const unsigned short* __restrict__ Wf,
                                               const float* __restrict__ asrc,
                                               const float* __restrict__ adst,
                                               unsigned short* __restrict__ h2,
                                               float* __restrict__ as, float* __restrict__ ad) {
  __shared__ unsigned short tile[4][16 * 64];    // 8 KB
  int wave = threadIdx.x >> 6, lane = threadIdx.x & 63;
  int strip = blockIdx.x * 4 + wave;
  if (strip >= kN / 16) return;
  int r0 = strip * 16;
  int m = lane & 15, quad = lane >> 4;
  const short8* xs = (const short8*)(o1 + (size_t)(r0 + m) * 128);
  short8 a0 = xs[quad], a1 = xs[quad + 4], a2 = xs[quad + 8], a3 = xs[quad + 12];
  const short8* wf = (const short8*)Wf;
  floatx4 acc[4];
#pragma unroll
  for (int nt = 0; nt < 4; ++nt) acc[nt] = floatx4{0.f, 0.f, 0.f, 0.f};
#pragma unroll
  for (int nt = 0; nt < 4; ++nt) {
    acc[nt] = __builtin_amdgcn_mfma_f32_16x16x32_bf16(a0, wf[(0 * 4 + nt) * 64 + lane], acc[nt], 0, 0, 0);
    acc[nt] = __builtin_amdgcn_mfma_f32_16x16x32_bf16(a1, wf[(1 * 4 + nt) * 64 + lane], acc[nt], 0, 0, 0);
    acc[nt] = __builtin_amdgcn_mfma_f32_16x16x32_bf16(a2, wf[(2 * 4 + nt) * 64 + lane], acc[nt], 0, 0, 0);
    acc[nt] = __builtin_amdgcn_mfma_f32_16x16x32_bf16(a3, wf[(3 * 4 + nt) * 64 + lane], acc[nt], 0, 0, 0);
  }
#pragma unroll
  for (int reg = 0; reg < 4; ++reg) {
    float s = 0.f, d = 0.f;
#pragma unroll
    for (int nt = 0; nt < 4; ++nt) {
      float v = acc[nt][reg];
      s += v * asrc[nt * 16 + m];
      d += v * adst[nt * 16 + m];
    }
#pragma unroll
    for (int off = 1; off < 16; off <<= 1) { s += __shfl_xor(s, off); d += __shfl_xor(d, off); }
    if (m == 0) { as[r0 + quad * 4 + reg] = s; ad[r0 + quad * 4 + reg] = d; }
  }
  unsigned short* tw = tile[wave];
#pragma unroll
  for (int nt = 0; nt < 4; ++nt)
#pragma unroll
    for (int reg = 0; reg < 4; ++reg)
      tw[(quad * 4 + reg) * 64 + nt * 16 + m] = f2bf(acc[nt][reg]);
  asm volatile("s_waitcnt lgkmcnt(0)" ::: "memory");
  const short8* tr = (const short8*)tw;
  short8* dstp = (short8*)(h2 + (size_t)r0 * 64);
#pragma unroll
  for (int sweep = 0; sweep < 2; ++sweep)
    dstp[sweep * 64 + lane] = tr[sweep * 64 + lane];
}

// ---------------- aggregation: one wave per dst node ----------------
// Phase 1: lane-parallel (one edge per lane) exact softmax stats (m, l).
// Phase 2: lane-parallel weight computation -> LDS, then lean serial gather loop.
// F==64: half-waves process 2 edges/iteration (row is only 32 dwords).
template <int F>
__global__ __launch_bounds__(256) void k_agg(const unsigned short* __restrict__ h,
                                             const int* __restrict__ row_start,
                                             const int* __restrict__ col,
                                             const float* __restrict__ as,
                                             const float* __restrict__ ad,
                                             const float* __restrict__ bias,
                                             unsigned short* __restrict__ out) {
  __shared__ int2 swb[4][64];
  int wave = threadIdx.x >> 6, lane = threadIdx.x & 63;
  int n = blockIdx.x * 4 + wave;
  if (n >= kN) return;
  int beg = row_start[n], end = row_start[n + 1];
  float adn = ad[n];

  // ---- phase 1: softmax stats ----
  float m = -1e30f, l = 0.f;
  for (int j0 = beg; j0 < end; j0 += 64) {
    int j = j0 + lane;
    float e = -1e30f;
    if (j < end) {
      int s = col[j];
      float t = as[s] + adn;
      e = t > 0.f ? t : kSlope * t;            // leaky_relu
    }
    float cm = e;
#pragma unroll
    for (int off = 32; off; off >>= 1) cm = fmaxf(cm, __shfl_xor(cm, off));
    float w = __expf(e - cm);                  // invalid lanes underflow to 0
    float cl = w;
#pragma unroll
    for (int off = 32; off; off >>= 1) cl += __shfl_xor(cl, off);
    float mn = fmaxf(m, cm);
    l = l * __expf(m - mn) + cl * __expf(cm - mn);
    m = mn;
  }
  float invl = 1.f / l;                        // >=1 edge guaranteed (self-loop)

  // ---- phase 2: weights -> LDS, gather-accumulate ----
  float a0 = 0.f, a1 = 0.f;
  int half = lane >> 5, hl = lane & 31;
  for (int j0 = beg; j0 < end; j0 += 64) {
    asm volatile("s_waitcnt lgkmcnt(0)" ::: "memory");  // prior chunk's reads done
    int j = j0 + lane;
    if (j < end) {
      int s = col[j];
      float t = as[s] + adn;
      float e = t > 0.f ? t : kSlope * t;
      float w = __expf(e - m) * invl;          // final attn weight (normalized)
      swb[wave][lane] = int2{s, (int)__float_as_int(w)};
    }
    asm volatile("s_waitcnt lgkmcnt(0)" ::: "memory");  // wave-local LDS RAW
    int cntc = min(64, end - j0);
    if (F == 128) {
#pragma unroll 2
      for (int k = 0; k < cntc; ++k) {
        int2 p = swb[wave][k];
        float w = __int_as_float(p.y);
        unsigned int v = ((const unsigned int*)(h + (size_t)p.x * 128))[lane];
        a0 += w * bf2f((unsigned short)(v & 0xffffu));
        a1 += w * bf2f((unsigned short)(v >> 16));
      }
    } else {
      for (int k = 0; k < cntc; k += 2) {
        int kk = k + half;
        if (kk < cntc) {
          int2 p = swb[wave][kk];
          float w = __int_as_float(p.y);
          unsigned int v = ((const unsigned int*)(h + (size_t)p.x * 64))[hl];
          a0 += w * bf2f((unsigned short)(v & 0xffffu));
          a1 += w * bf2f((unsigned short)(v >> 16));
        }
      }
    }
  }
  if (F == 128) {
    float o0 = fmaxf(a0 + bias[2 * lane], 0.f);
    float o1 = fmaxf(a1 + bias[2 * lane + 1], 0.f);
    unsigned int packed = ((unsigned int)f2bf(o1) << 16) | f2bf(o0);
    ((unsigned int*)(out + (size_t)n * 128))[lane] = packed;
  } else {
    a0 += __shfl_xor(a0, 32);                  // combine the two half-waves
    a1 += __shfl_xor(a1, 32);
    if (half == 0) {
      float o0 = fmaxf(a0 + bias[2 * hl], 0.f);
      float o1 = fmaxf(a1 + bias[2 * hl + 1], 0.f);
      unsigned int packed = ((unsigned int)f2bf(o1) << 16) | f2bf(o0);
      ((unsigned int*)(out + (size_t)n * 64))[hl] = packed;
    }
  }
}

// ---------------- FC head: per masked row, fused fc1(relu)+fc2, fp32 out ----------------
__global__ __launch_bounds__(128) void k_fc(const unsigned short* __restrict__ o2,
                                            const int* __restrict__ mask,
                                            const float* __restrict__ fc1w,
                                            const float* __restrict__ fc1b,
                                            const float* __restrict__ fc2w,
                                            const float* __restrict__ fc2b,
                                            float* __restrict__ out) {
  __shared__ float hm[64];
  __shared__ float z[128];
  int b = blockIdx.x, t = threadIdx.x;
  int row = mask[b];
  if (t < 64) hm[t] = bf2f(o2[(size_t)row * 64 + t]);
  __syncthreads();
  float a = fc1b[t];
#pragma unroll 8
  for (int k = 0; k < 64; ++k) a += hm[k] * fc1w[k * 128 + t];
  z[t] = fmaxf(a, 0.f);
  __syncthreads();
  if (t < 10) {
    float o = fc2b[t];
#pragma unroll 8
    for (int k = 0; k < 128; ++k) o += z[k] * fc2w[k * 10 + t];
    out[(size_t)b * 10 + t] = o;
  }
}

extern "C" void kernel_launch(void* const* d_in, const int* in_sizes, int n_in,
                              void* d_out, int out_size, void* d_ws, size_t ws_size,
                              hipStream_t stream) {
  const float* x     = (const float*)d_in[0];
  const int*   ei    = (const int*)d_in[1];     // [2,E] as int32 (harness converts)
  const int*   mask  = (const int*)d_in[2];
  const float* W1    = (const float*)d_in[3];
  const float* asrc1 = (const float*)d_in[4];
  const float* adst1 = (const float*)d_in[5];
  const float* b1    = (const float*)d_in[6];
  const float* W2    = (const float*)d_in[7];
  const float* asrc2 = (const float*)d_in[8];
  const float* adst2 = (const float*)d_in[9];
  const float* b2    = (const float*)d_in[10];
  const float* fc1w  = (const float*)d_in[11];
  const float* fc1b  = (const float*)d_in[12];
  const float* fc2w  = (const float*)d_in[13];
  const float* fc2b  = (const float*)d_in[14];
  float* out = (float*)d_out;

  const int* esrc = ei;
  const int* edst = ei + kE;

  // -------- workspace layout (small arrays first; total ~62 MB) --------
  char* ws = (char*)d_ws;
  size_t off = 0;
  auto alloc = [&](size_t bytes) -> void* {
    void* p = ws + off;
    off = (off + bytes + 255) & ~(size_t)255;
    return p;
  };
  unsigned short* Wf1    = (unsigned short*)alloc(128 * 128 * 2);       // 32 KB
  unsigned short* Wf2    = (unsigned short*)alloc(128 * 64 * 2);        // 16 KB
  int*            rstart = (int*)alloc((size_t)(kN + 1) * 4);           // 0.4 MB
  int*            counts = (int*)alloc((size_t)kN * 4);                 // 0.4 MB
  int*            cursor = (int*)alloc((size_t)kN * 4);                 // 0.4 MB
  int*            bsum   = (int*)alloc((size_t)kScanBlocks * 4);        // tiny
  float*          as1    = (float*)alloc((size_t)kN * 4);
  float*          ad1    = (float*)alloc((size_t)kN * 4);
  float*          as2    = (float*)alloc((size_t)kN * 4);
  float*          ad2    = (float*)alloc((size_t)kN * 4);               // 1.6 MB total
  int*            colidx = (int*)alloc((size_t)kTotE * 4);              // 6.8 MB
  unsigned short* h1     = (unsigned short*)alloc((size_t)kN * 128 * 2);// 25.6 MB
  unsigned short* o1     = (unsigned short*)alloc((size_t)kN * 128 * 2);// 25.6 MB
  // h2/o2 alias the h1 region (h1 dead after k_agg<128>)
  unsigned short* h2 = h1;                       // 12.8 MB
  unsigned short* o2 = h1 + (size_t)kN * 64;     // 12.8 MB
  (void)ws_size; (void)in_sizes; (void)n_in; (void)out_size;

  // CSR build (ws re-poisoned every call -> rebuild each time)
  k_init_counts<<<(kN + 255) / 256, 256, 0, stream>>>(counts);
  k_count<<<(kE + 255) / 256, 256, 0, stream>>>(edst, counts);
  k_scan_part<<<kScanBlocks, 256, 0, stream>>>(counts, bsum);
  k_scan_bsum<<<1, 128, 0, stream>>>(bsum, rstart);
  k_scan_write<<<kScanBlocks, 256, 0, stream>>>(counts, bsum, rstart, cursor);
  k_fill<<<(kTotE + 255) / 256, 256, 0, stream>>>(esrc, edst, cursor, colidx);

  // Weight swizzle (fp32 -> bf16) for MFMA B-frags
  k_wprep<<<(128 * 128 + 255) / 256, 256, 0, stream>>>(W1, Wf1, 128, 128);
  k_wprep<<<(128 * 64 + 255) / 256, 256, 0, stream>>>(W2, Wf2, 128, 64);

  const int gemmBlocks = (kN / 16 + 3) / 4;   // 6250 strips, 4 waves/block
  const int nodeBlocks = (kN + 3) / 4;        // 1 wave per node

  // Layer 1
  k_gemm1<<<gemmBlocks, 256, 0, stream>>>(x, Wf1, asrc1, adst1, h1, as1, ad1);
  k_agg<128><<<nodeBlocks, 256, 0, stream>>>(h1, rstart, colidx, as1, ad1, b1, o1);
  // Layer 2 (h2/o2 live in the dead h1 region)
  k_gemm2<<<gemmBlocks, 256, 0, stream>>>(o1, Wf2, asrc2, adst2, h2, as2, ad2);
  k_agg<64><<<nodeBlocks, 256, 0, stream>>>(h2, rstart, colidx, as2, ad2, b2, o2);
  // FC head
  k_fc<<<kM, 128, 0, stream>>>(o2, mask, fc1w, fc1b, fc2w, fc2b, out);
}

// Round 6
// 409.526 us; speedup vs baseline: 2.5090x; 1.3786x over previous
//
#include <hip/hip_runtime.h>

constexpr int kN    = 100000;   // nodes
constexpr int kE    = 1600000;  // random edges
constexpr int kTotE = kE + kN;  // + self loops
constexpr int kM    = 20000;    // masked rows
constexpr float kSlope = 0.2f;

// bucketed CSR build: buckets of 128 consecutive dst nodes
constexpr int kNB   = (kN + 127) >> 7;          // 782 buckets
constexpr int kBCap = 3072;                      // per-bucket pair capacity (mean 2304, +16 sigma)
constexpr int kEB   = 4096;                      // edge-stream elems per scatter block
constexpr int kSB   = (kTotE + kEB - 1) / kEB;   // 416 scatter blocks

typedef short short8  __attribute__((ext_vector_type(8)));
typedef float floatx4 __attribute__((ext_vector_type(4)));

__device__ __forceinline__ float bf2f(unsigned short u) {
  union { unsigned int i; float f; } v; v.i = ((unsigned int)u) << 16; return v.f;
}
__device__ __forceinline__ unsigned short f2bf(float f) {
  union { float f; unsigned int i; } v; v.f = f;
  unsigned int x = v.i;
  x += 0x7fffu + ((x >> 16) & 1u);   // RNE
  return (unsigned short)(x >> 16);
}
__device__ __forceinline__ short8 pack8(float4 u, float4 v) {
  short8 r;
  r[0] = (short)f2bf(u.x); r[1] = (short)f2bf(u.y);
  r[2] = (short)f2bf(u.z); r[3] = (short)f2bf(u.w);
  r[4] = (short)f2bf(v.x); r[5] = (short)f2bf(v.y);
  r[6] = (short)f2bf(v.z); r[7] = (short)f2bf(v.w);
  return r;
}

// ---------------- CSR build, bucketed ----------------
// Step 1: scatter (src,dst) pairs into per-bucket regions. Per-block LDS
// histogram -> one global atomicAdd per touched bin -> run-contiguous writes
// (time-local, so lines merge in L2 instead of 64B/edge writeback).
__global__ __launch_bounds__(256) void k_bscatter(const int* __restrict__ src,
                                                  const int* __restrict__ dst,
                                                  int* __restrict__ bucketCursor,
                                                  int2* __restrict__ pairs) {
  __shared__ int hist[kNB];
  __shared__ int runBase[kNB];
  __shared__ int binCur[kNB];
  int b = blockIdx.x, t = threadIdx.x;
  for (int i = t; i < kNB; i += 256) hist[i] = 0;
  __syncthreads();
  int i0 = b * kEB;
#pragma unroll
  for (int k = 0; k < kEB / 256; ++k) {
    int i = i0 + t + k * 256;
    if (i < kTotE) {
      int d = (i < kE) ? dst[i] : (i - kE);
      atomicAdd(&hist[d >> 7], 1);
    }
  }
  __syncthreads();
  for (int i = t; i < kNB; i += 256) {
    int c = hist[i];
    int base = -1;
    if (c) {
      base = atomicAdd(&bucketCursor[i], c);
      if (base + c > kBCap) base = -1;      // overflow guard (never expected)
    }
    runBase[i] = base;
    binCur[i] = 0;
  }
  __syncthreads();
#pragma unroll
  for (int k = 0; k < kEB / 256; ++k) {
    int i = i0 + t + k * 256;
    if (i < kTotE) {
      int s, d;
      if (i < kE) { s = src[i]; d = dst[i]; }
      else        { s = d = i - kE; }
      int bin = d >> 7;
      int lp = atomicAdd(&binCur[bin], 1);
      int rb = runBase[bin];
      if (rb >= 0) pairs[(size_t)bin * kBCap + rb + lp] = int2{s, d};
    }
  }
}

// Step 2: exclusive scan of bucket counts -> dense colidx bases.
__global__ __launch_bounds__(1024) void k_bscan(const int* __restrict__ bucketCursor,
                                                int* __restrict__ colBase,
                                                int* __restrict__ rstart) {
  __shared__ int sh[1024];
  int t = threadIdx.x;
  int v = (t < kNB) ? min(bucketCursor[t], kBCap) : 0;
  sh[t] = v;
  __syncthreads();
  for (int off = 1; off < 1024; off <<= 1) {
    int u = (t >= off) ? sh[t - off] : 0;
    __syncthreads();
    sh[t] += u;
    __syncthreads();
  }
  if (t < kNB) colBase[t] = sh[t] - v;        // exclusive prefix
  if (t == kNB - 1) { colBase[kNB] = sh[t]; rstart[kN] = sh[t]; }
}

// Step 3: per-bucket CSR finalize. Node histogram + LDS scan -> rstart;
// LDS counting-sort by node -> fully coalesced colidx writes.
__global__ __launch_bounds__(256) void k_bucket_csr(const int2* __restrict__ pairs,
                                                    const int* __restrict__ bucketCursor,
                                                    const int* __restrict__ colBase,
                                                    int* __restrict__ rstart,
                                                    int* __restrict__ colidx) {
  __shared__ int2 pl[kBCap];                  // 24 KB
  __shared__ int  colLDS[kBCap];              // 12 KB
  __shared__ int  nhist[128], nstart[128], ncur[128], scanbuf[128];
  int b = blockIdx.x, t = threadIdx.x;
  int cnt  = min(bucketCursor[b], kBCap);
  int base = colBase[b];
  if (t < 128) { nhist[t] = 0; ncur[t] = 0; }
  __syncthreads();
  for (int j = t; j < cnt; j += 256) {
    int2 p = pairs[(size_t)b * kBCap + j];
    pl[j] = p;
    atomicAdd(&nhist[p.y & 127], 1);
  }
  __syncthreads();
  if (t < 128) scanbuf[t] = nhist[t];
  __syncthreads();
  for (int off = 1; off < 128; off <<= 1) {   // inclusive Hillis-Steele
    int u = (t < 128 && t >= off) ? scanbuf[t - off] : 0;
    __syncthreads();
    if (t < 128) scanbuf[t] += u;
    __syncthreads();
  }
  if (t < 128) nstart[t] = scanbuf[t] - nhist[t];   // exclusive
  __syncthreads();
  int nodes = min(128, kN - b * 128);
  if (t < nodes) rstart[b * 128 + t] = base + nstart[t];
  for (int j = t; j < cnt; j += 256) {
    int2 p = pl[j];
    int nl = p.y & 127;
    int lp = atomicAdd(&ncur[nl], 1);
    colLDS[nstart[nl] + lp] = p.x;
  }
  __syncthreads();
  for (int j = t; j < cnt; j += 256)
    colidx[base + j] = colLDS[j];
}

// ---------------- weight pre-swizzle (fp32 -> bf16) into MFMA B-frag order ----------------
__global__ void k_wprep(const float* __restrict__ W,
                        unsigned short* __restrict__ Wf, int K, int Fo) {
  int idx = blockIdx.x * 256 + threadIdx.x;
  if (idx >= K * Fo) return;
  int j    = idx & 7;
  int lane = (idx >> 3) & 63;
  int t    = idx >> 9;
  int NT = Fo >> 4;
  int kt = t / NT, nt = t - kt * NT;
  int k = kt * 32 + ((lane >> 4) & 3) * 8 + j;
  int n = nt * 16 + (lane & 15);
  Wf[idx] = f2bf(W[k * Fo + n]);
}

// ---------------- GEMM layer1: h1[N,128](bf16) = x(fp32) @ W1, + alpha dots (fp32) ----------------
__global__ __launch_bounds__(256) void k_gemm1(const float* __restrict__ x,
                                               const unsigned short* __restrict__ Wf,
                                               const float* __restrict__ asrc,
                                               const float* __restrict__ adst,
                                               unsigned short* __restrict__ h1,
                                               float* __restrict__ as, float* __restrict__ ad) {
  __shared__ unsigned short tile[4][16 * 128];   // 16 KB, per-wave regions
  int wave = threadIdx.x >> 6, lane = threadIdx.x & 63;
  int strip = blockIdx.x * 4 + wave;
  if (strip >= kN / 16) return;
  int r0 = strip * 16;
  int m = lane & 15, quad = lane >> 4;
  const float4* xf = (const float4*)(x + (size_t)(r0 + m) * 128);   // 32 float4 per row
  short8 a0 = pack8(xf[quad * 2 + 0],  xf[quad * 2 + 1]);           // k-tile 0
  short8 a1 = pack8(xf[quad * 2 + 8],  xf[quad * 2 + 9]);           // k-tile 1
  short8 a2 = pack8(xf[quad * 2 + 16], xf[quad * 2 + 17]);          // k-tile 2
  short8 a3 = pack8(xf[quad * 2 + 24], xf[quad * 2 + 25]);          // k-tile 3
  const short8* wf = (const short8*)Wf;
  floatx4 acc[8];
#pragma unroll
  for (int nt = 0; nt < 8; ++nt) acc[nt] = floatx4{0.f, 0.f, 0.f, 0.f};
#pragma unroll
  for (int nt = 0; nt < 8; ++nt) {
    acc[nt] = __builtin_amdgcn_mfma_f32_16x16x32_bf16(a0, wf[(0 * 8 + nt) * 64 + lane], acc[nt], 0, 0, 0);
    acc[nt] = __builtin_amdgcn_mfma_f32_16x16x32_bf16(a1, wf[(1 * 8 + nt) * 64 + lane], acc[nt], 0, 0, 0);
    acc[nt] = __builtin_amdgcn_mfma_f32_16x16x32_bf16(a2, wf[(2 * 8 + nt) * 64 + lane], acc[nt], 0, 0, 0);
    acc[nt] = __builtin_amdgcn_mfma_f32_16x16x32_bf16(a3, wf[(3 * 8 + nt) * 64 + lane], acc[nt], 0, 0, 0);
  }
  // alpha_s / alpha_d from fp32 accumulators. acc[nt][reg] = h[r0+quad*4+reg][nt*16+m]
#pragma unroll
  for (int reg = 0; reg < 4; ++reg) {
    float s = 0.f, d = 0.f;
#pragma unroll
    for (int nt = 0; nt < 8; ++nt) {
      float v = acc[nt][reg];
      s += v * asrc[nt * 16 + m];
      d += v * adst[nt * 16 + m];
    }
#pragma unroll
    for (int off = 1; off < 16; off <<= 1) { s += __shfl_xor(s, off); d += __shfl_xor(d, off); }
    if (m == 0) { as[r0 + quad * 4 + reg] = s; ad[r0 + quad * 4 + reg] = d; }
  }
  // repack to bf16 via per-wave LDS tile, then coalesced 16B stores
  unsigned short* tw = tile[wave];
#pragma unroll
  for (int nt = 0; nt < 8; ++nt)
#pragma unroll
    for (int reg = 0; reg < 4; ++reg)
      tw[(quad * 4 + reg) * 128 + nt * 16 + m] = f2bf(acc[nt][reg]);
  asm volatile("s_waitcnt lgkmcnt(0)" ::: "memory");   // wave-local LDS RAW
  const short8* tr = (const short8*)tw;
  short8* dstp = (short8*)(h1 + (size_t)r0 * 128);
#pragma unroll
  for (int sweep = 0; sweep < 4; ++sweep)
    dstp[sweep * 64 + lane] = tr[sweep * 64 + lane];
}

// ---------------- GEMM layer2: h2[N,64](bf16) = o1(bf16) @ W2, + alpha dots ----------------
__global__ __launch_bounds__(256) void k_gemm2(const unsigned short* __restrict__ o1,
                                               const unsigned short* __restrict__ Wf,
                                               const float* __restrict__ asrc,
                                               const float* __restrict__ adst,
                                               unsigned short* __restrict__ h2,
                                               float* __restrict__ as, float* __restrict__ ad) {
  __shared__ unsigned short tile[4][16 * 64];    // 8 KB
  int wave = threadIdx.x >> 6, lane = threadIdx.x & 63;
  int strip = blockIdx.x * 4 + wave;
  if (strip >= kN / 16) return;
  int r0 = strip * 16;
  int m = lane & 15, quad = lane >> 4;
  const short8* xs = (const short8*)(o1 + (size_t)(r0 + m) * 128);
  short8 a0 = xs[quad], a1 = xs[quad + 4], a2 = xs[quad + 8], a3 = xs[quad + 12];
  const short8* wf = (const short8*)Wf;
  floatx4 acc[4];
#pragma unroll
  for (int nt = 0; nt < 4; ++nt) acc[nt] = floatx4{0.f, 0.f, 0.f, 0.f};
#pragma unroll
  for (int nt = 0; nt < 4; ++nt) {
    acc[nt] = __builtin_amdgcn_mfma_f32_16x16x32_bf16(a0, wf[(0 * 4 + nt) * 64 + lane], acc[nt], 0, 0, 0);
    acc[nt] = __builtin_amdgcn_mfma_f32_16x16x32_bf16(a1, wf[(1 * 4 + nt) * 64 + lane], acc[nt], 0, 0, 0);
    acc[nt] = __builtin_amdgcn_mfma_f32_16x16x32_bf16(a2, wf[(2 * 4 + nt) * 64 + lane], acc[nt], 0, 0, 0);
    acc[nt] = __builtin_amdgcn_mfma_f32_16x16x32_bf16(a3, wf[(3 * 4 + nt) * 64 + lane], acc[nt], 0, 0, 0);
  }
#pragma unroll
  for (int reg = 0; reg < 4; ++reg) {
    float s = 0.f, d = 0.f;
#pragma unroll
    for (int nt = 0; nt < 4; ++nt) {
      float v = acc[nt][reg];
      s += v * asrc[nt * 16 + m];
      d += v * adst[nt * 16 + m];
    }
#pragma unroll
    for (int off = 1; off < 16; off <<= 1) { s += __shfl_xor(s, off); d += __shfl_xor(d, off); }
    if (m == 0) { as[r0 + quad * 4 + reg] = s; ad[r0 + quad * 4 + reg] = d; }
  }
  unsigned short* tw = tile[wave];
#pragma unroll
  for (int nt = 0; nt < 4; ++nt)
#pragma unroll
    for (int reg = 0; reg < 4; ++reg)
      tw[(quad * 4 + reg) * 64 + nt * 16 + m] = f2bf(acc[nt][reg]);
  asm volatile("s_waitcnt lgkmcnt(0)" ::: "memory");
  const short8* tr = (const short8*)tw;
  short8* dstp = (short8*)(h2 + (size_t)r0 * 64);
#pragma unroll
  for (int sweep = 0; sweep < 2; ++sweep)
    dstp[sweep * 64 + lane] = tr[sweep * 64 + lane];
}

// ---------------- aggregation: one wave per dst node ----------------
template <int F>
__global__ __launch_bounds__(256) void k_agg(const unsigned short* __restrict__ h,
                                             const int* __restrict__ row_start,
                                             const int* __restrict__ col,
                                             const float* __restrict__ as,
                                             const float* __restrict__ ad,
                                             const float* __restrict__ bias,
                                             unsigned short* __restrict__ out) {
  __shared__ int2 swb[4][64];
  int wave = threadIdx.x >> 6, lane = threadIdx.x & 63;
  int n = blockIdx.x * 4 + wave;
  if (n >= kN) return;
  int beg = row_start[n], end = row_start[n + 1];
  float adn = ad[n];

  // ---- phase 1: softmax stats ----
  float m = -1e30f, l = 0.f;
  for (int j0 = beg; j0 < end; j0 += 64) {
    int j = j0 + lane;
    float e = -1e30f;
    if (j < end) {
      int s = col[j];
      float t = as[s] + adn;
      e = t > 0.f ? t : kSlope * t;            // leaky_relu
    }
    float cm = e;
#pragma unroll
    for (int off = 32; off; off >>= 1) cm = fmaxf(cm, __shfl_xor(cm, off));
    float w = __expf(e - cm);                  // invalid lanes underflow to 0
    float cl = w;
#pragma unroll
    for (int off = 32; off; off >>= 1) cl += __shfl_xor(cl, off);
    float mn = fmaxf(m, cm);
    l = l * __expf(m - mn) + cl * __expf(cm - mn);
    m = mn;
  }
  float invl = 1.f / l;                        // >=1 edge guaranteed (self-loop)

  // ---- phase 2: weights -> LDS, gather-accumulate ----
  float a0 = 0.f, a1 = 0.f;
  int half = lane >> 5, hl = lane & 31;
  for (int j0 = beg; j0 < end; j0 += 64) {
    asm volatile("s_waitcnt lgkmcnt(0)" ::: "memory");  // prior chunk's reads done
    int j = j0 + lane;
    if (j < end) {
      int s = col[j];
      float t = as[s] + adn;
      float e = t > 0.f ? t : kSlope * t;
      float w = __expf(e - m) * invl;          // final attn weight (normalized)
      swb[wave][lane] = int2{s, (int)__float_as_int(w)};
    }
    asm volatile("s_waitcnt lgkmcnt(0)" ::: "memory");  // wave-local LDS RAW
    int cntc = min(64, end - j0);
    if (F == 128) {
#pragma unroll 2
      for (int k = 0; k < cntc; ++k) {
        int2 p = swb[wave][k];
        float w = __int_as_float(p.y);
        unsigned int v = ((const unsigned int*)(h + (size_t)p.x * 128))[lane];
        a0 += w * bf2f((unsigned short)(v & 0xffffu));
        a1 += w * bf2f((unsigned short)(v >> 16));
      }
    } else {
      for (int k = 0; k < cntc; k += 2) {
        int kk = k + half;
        if (kk < cntc) {
          int2 p = swb[wave][kk];
          float w = __int_as_float(p.y);
          unsigned int v = ((const unsigned int*)(h + (size_t)p.x * 64))[hl];
          a0 += w * bf2f((unsigned short)(v & 0xffffu));
          a1 += w * bf2f((unsigned short)(v >> 16));
        }
      }
    }
  }
  if (F == 128) {
    float o0 = fmaxf(a0 + bias[2 * lane], 0.f);
    float o1 = fmaxf(a1 + bias[2 * lane + 1], 0.f);
    unsigned int packed = ((unsigned int)f2bf(o1) << 16) | f2bf(o0);
    ((unsigned int*)(out + (size_t)n * 128))[lane] = packed;
  } else {
    a0 += __shfl_xor(a0, 32);                  // combine the two half-waves
    a1 += __shfl_xor(a1, 32);
    if (half == 0) {
      float o0 = fmaxf(a0 + bias[2 * hl], 0.f);
      float o1 = fmaxf(a1 + bias[2 * hl + 1], 0.f);
      unsigned int packed = ((unsigned int)f2bf(o1) << 16) | f2bf(o0);
      ((unsigned int*)(out + (size_t)n * 64))[hl] = packed;
    }
  }
}

// ---------------- FC head: per masked row, fused fc1(relu)+fc2, fp32 out ----------------
__global__ __launch_bounds__(128) void k_fc(const unsigned short* __restrict__ o2,
                                            const int* __restrict__ mask,
                                            const float* __restrict__ fc1w,
                                            const float* __restrict__ fc1b,
                                            const float* __restrict__ fc2w,
                                            const float* __restrict__ fc2b,
                                            float* __restrict__ out) {
  __shared__ float hm[64];
  __shared__ float z[128];
  int b = blockIdx.x, t = threadIdx.x;
  int row = mask[b];
  if (t < 64) hm[t] = bf2f(o2[(size_t)row * 64 + t]);
  __syncthreads();
  float a = fc1b[t];
#pragma unroll 8
  for (int k = 0; k < 64; ++k) a += hm[k] * fc1w[k * 128 + t];
  z[t] = fmaxf(a, 0.f);
  __syncthreads();
  if (t < 10) {
    float o = fc2b[t];
#pragma unroll 8
    for (int k = 0; k < 128; ++k) o += z[k] * fc2w[k * 10 + t];
    out[(size_t)b * 10 + t] = o;
  }
}

extern "C" void kernel_launch(void* const* d_in, const int* in_sizes, int n_in,
                              void* d_out, int out_size, void* d_ws, size_t ws_size,
                              hipStream_t stream) {
  const float* x     = (const float*)d_in[0];
  const int*   ei    = (const int*)d_in[1];     // [2,E] as int32 (harness converts)
  const int*   mask  = (const int*)d_in[2];
  const float* W1    = (const float*)d_in[3];
  const float* asrc1 = (const float*)d_in[4];
  const float* adst1 = (const float*)d_in[5];
  const float* b1    = (const float*)d_in[6];
  const float* W2    = (const float*)d_in[7];
  const float* asrc2 = (const float*)d_in[8];
  const float* adst2 = (const float*)d_in[9];
  const float* b2    = (const float*)d_in[10];
  const float* fc1w  = (const float*)d_in[11];
  const float* fc1b  = (const float*)d_in[12];
  const float* fc2w  = (const float*)d_in[13];
  const float* fc2b  = (const float*)d_in[14];
  float* out = (float*)d_out;

  const int* esrc = ei;
  const int* edst = ei + kE;

  // -------- workspace layout (total ~80 MB) --------
  char* ws = (char*)d_ws;
  size_t off = 0;
  auto alloc = [&](size_t bytes) -> void* {
    void* p = ws + off;
    off = (off + bytes + 255) & ~(size_t)255;
    return p;
  };
  unsigned short* Wf1     = (unsigned short*)alloc(128 * 128 * 2);        // 32 KB
  unsigned short* Wf2     = (unsigned short*)alloc(128 * 64 * 2);         // 16 KB
  int*            rstart  = (int*)alloc((size_t)(kN + 1) * 4);            // 0.4 MB
  int*            bcursor = (int*)alloc((size_t)kNB * 4);                 // 3.1 KB
  int*            colBase = (int*)alloc((size_t)(kNB + 1) * 4);           // 3.1 KB
  float*          as1     = (float*)alloc((size_t)kN * 4);
  float*          ad1     = (float*)alloc((size_t)kN * 4);
  float*          as2     = (float*)alloc((size_t)kN * 4);
  float*          ad2     = (float*)alloc((size_t)kN * 4);                // 1.6 MB total
  int*            colidx  = (int*)alloc((size_t)kTotE * 4);               // 6.8 MB
  int2*           pairs   = (int2*)alloc((size_t)kNB * kBCap * 8);        // 19.2 MB
  unsigned short* h1      = (unsigned short*)alloc((size_t)kN * 128 * 2); // 25.6 MB
  unsigned short* o1      = (unsigned short*)alloc((size_t)kN * 128 * 2); // 25.6 MB
  // h2/o2 alias the h1 region (h1 dead after k_agg<128>)
  unsigned short* h2 = h1;                       // 12.8 MB
  unsigned short* o2 = h1 + (size_t)kN * 64;     // 12.8 MB
  (void)ws_size; (void)in_sizes; (void)n_in; (void)out_size;

  // CSR build, bucketed (ws re-poisoned every call -> rebuild each time)
  hipMemsetAsync(bcursor, 0, (size_t)kNB * 4, stream);
  k_bscatter<<<kSB, 256, 0, stream>>>(esrc, edst, bcursor, pairs);
  k_bscan<<<1, 1024, 0, stream>>>(bcursor, colBase, rstart);
  k_bucket_csr<<<kNB, 256, 0, stream>>>(pairs, bcursor, colBase, rstart, colidx);

  // Weight swizzle (fp32 -> bf16) for MFMA B-frags
  k_wprep<<<(128 * 128 + 255) / 256, 256, 0, stream>>>(W1, Wf1, 128, 128);
  k_wprep<<<(128 * 64 + 255) / 256, 256, 0, stream>>>(W2, Wf2, 128, 64);

  const int gemmBlocks = (kN / 16 + 3) / 4;   // 6250 strips, 4 waves/block
  const int nodeBlocks = (kN + 3) / 4;        // 1 wave per node

  // Layer 1
  k_gemm1<<<gemmBlocks, 256, 0, stream>>>(x, Wf1, asrc1, adst1, h1, as1, ad1);
  k_agg<128><<<nodeBlocks, 256, 0, stream>>>(h1, rstart, colidx, as1, ad1, b1, o1);
  // Layer 2 (h2/o2 live in the dead h1 region)
  k_gemm2<<<gemmBlocks, 256, 0, stream>>>(o1, Wf2, asrc2, adst2, h2, as2, ad2);
  k_agg<64><<<nodeBlocks, 256, 0, stream>>>(h2, rstart, colidx, as2, ad2, b2, o2);
  // FC head
  k_fc<<<kM, 128, 0, stream>>>(o2, mask, fc1w, fc1b, fc2w, fc2b, out);
}

// Round 7
// 325.934 us; speedup vs baseline: 3.1524x; 1.2565x over previous
//
#include <hip/hip_runtime.h>

constexpr int kN    = 100000;   // nodes
constexpr int kE    = 1600000;  // random edges
constexpr int kTotE = kE + kN;  // + self loops
constexpr int kM    = 20000;    // masked rows
constexpr float kSlope = 0.2f;

// bucketed CSR build: buckets of 128 consecutive dst nodes
constexpr int kNB   = (kN + 127) >> 7;          // 782 buckets
constexpr int kBCap = 3072;                      // per-bucket pair capacity (mean 2304)
constexpr int kEB   = 4096;                      // edge-stream elems per scatter block
constexpr int kSB   = (kTotE + kEB - 1) / kEB;   // 416 scatter blocks

typedef short short8  __attribute__((ext_vector_type(8)));
typedef float floatx4 __attribute__((ext_vector_type(4)));

__device__ __forceinline__ float bf2f(unsigned short u) {
  union { unsigned int i; float f; } v; v.i = ((unsigned int)u) << 16; return v.f;
}
__device__ __forceinline__ unsigned short f2bf(float f) {
  union { float f; unsigned int i; } v; v.f = f;
  unsigned int x = v.i;
  x += 0x7fffu + ((x >> 16) & 1u);   // RNE
  return (unsigned short)(x >> 16);
}
__device__ __forceinline__ short8 pack8(float4 u, float4 v) {
  short8 r;
  r[0] = (short)f2bf(u.x); r[1] = (short)f2bf(u.y);
  r[2] = (short)f2bf(u.z); r[3] = (short)f2bf(u.w);
  r[4] = (short)f2bf(v.x); r[5] = (short)f2bf(v.y);
  r[6] = (short)f2bf(v.z); r[7] = (short)f2bf(v.w);
  return r;
}

// ---------------- CSR build, bucketed ----------------
// pairs packed: (dst&127)<<17 | src   (src < 2^17, local node 7 bits)
__global__ __launch_bounds__(256) void k_bscatter(const int* __restrict__ src,
                                                  const int* __restrict__ dst,
                                                  int* __restrict__ bucketCursor,
                                                  int* __restrict__ pairs) {
  __shared__ int hist[kNB];
  __shared__ int runBase[kNB];
  __shared__ int binCur[kNB];
  int b = blockIdx.x, t = threadIdx.x;
  for (int i = t; i < kNB; i += 256) hist[i] = 0;
  __syncthreads();
  int i0 = b * kEB;
#pragma unroll
  for (int k = 0; k < kEB / 256; ++k) {
    int i = i0 + t + k * 256;
    if (i < kTotE) {
      int d = (i < kE) ? dst[i] : (i - kE);
      atomicAdd(&hist[d >> 7], 1);
    }
  }
  __syncthreads();
  for (int i = t; i < kNB; i += 256) {
    int c = hist[i];
    int base = -1;
    if (c) {
      base = atomicAdd(&bucketCursor[i], c);
      if (base + c > kBCap) base = -1;      // overflow guard (never expected)
    }
    runBase[i] = base;
    binCur[i] = 0;
  }
  __syncthreads();
#pragma unroll
  for (int k = 0; k < kEB / 256; ++k) {
    int i = i0 + t + k * 256;
    if (i < kTotE) {
      int s, d;
      if (i < kE) { s = src[i]; d = dst[i]; }
      else        { s = d = i - kE; }
      int bin = d >> 7;
      int lp = atomicAdd(&binCur[bin], 1);
      int rb = runBase[bin];
      if (rb >= 0) pairs[(size_t)bin * kBCap + rb + lp] = ((d & 127) << 17) | s;
    }
  }
}

__global__ __launch_bounds__(1024) void k_bscan(const int* __restrict__ bucketCursor,
                                                int* __restrict__ colBase,
                                                int* __restrict__ rstart) {
  __shared__ int sh[1024];
  int t = threadIdx.x;
  int v = (t < kNB) ? min(bucketCursor[t], kBCap) : 0;
  sh[t] = v;
  __syncthreads();
  for (int off = 1; off < 1024; off <<= 1) {
    int u = (t >= off) ? sh[t - off] : 0;
    __syncthreads();
    sh[t] += u;
    __syncthreads();
  }
  if (t < kNB) colBase[t] = sh[t] - v;        // exclusive prefix
  if (t == kNB - 1) { colBase[kNB] = sh[t]; rstart[kN] = sh[t]; }
}

__global__ __launch_bounds__(256) void k_bucket_csr(const int* __restrict__ pairs,
                                                    const int* __restrict__ bucketCursor,
                                                    const int* __restrict__ colBase,
                                                    int* __restrict__ rstart,
                                                    int* __restrict__ colidx) {
  __shared__ int pl[kBCap];                   // 12 KB
  __shared__ int colLDS[kBCap];               // 12 KB
  __shared__ int nhist[128], nstart[128], ncur[128], scanbuf[128];
  int b = blockIdx.x, t = threadIdx.x;
  int cnt  = min(bucketCursor[b], kBCap);
  int base = colBase[b];
  if (t < 128) { nhist[t] = 0; ncur[t] = 0; }
  __syncthreads();
  for (int j = t; j < cnt; j += 256) {
    int p = pairs[(size_t)b * kBCap + j];
    pl[j] = p;
    atomicAdd(&nhist[(p >> 17) & 127], 1);
  }
  __syncthreads();
  if (t < 128) scanbuf[t] = nhist[t];
  __syncthreads();
  for (int off = 1; off < 128; off <<= 1) {   // inclusive Hillis-Steele
    int u = (t < 128 && t >= off) ? scanbuf[t - off] : 0;
    __syncthreads();
    if (t < 128) scanbuf[t] += u;
    __syncthreads();
  }
  if (t < 128) nstart[t] = scanbuf[t] - nhist[t];   // exclusive
  __syncthreads();
  int nodes = min(128, kN - b * 128);
  if (t < nodes) rstart[b * 128 + t] = base + nstart[t];
  for (int j = t; j < cnt; j += 256) {
    int p = pl[j];
    int nl = (p >> 17) & 127;
    int lp = atomicAdd(&ncur[nl], 1);
    colLDS[nstart[nl] + lp] = p & 0x1FFFF;
  }
  __syncthreads();
  for (int j = t; j < cnt; j += 256)
    colidx[base + j] = colLDS[j];
}

// ---------------- weight pre-swizzle (fp32 -> bf16) into MFMA B-frag order ----------------
__global__ void k_wprep(const float* __restrict__ W,
                        unsigned short* __restrict__ Wf, int K, int Fo) {
  int idx = blockIdx.x * 256 + threadIdx.x;
  if (idx >= K * Fo) return;
  int j    = idx & 7;
  int lane = (idx >> 3) & 63;
  int t    = idx >> 9;
  int NT = Fo >> 4;
  int kt = t / NT, nt = t - kt * NT;
  int k = kt * 32 + ((lane >> 4) & 3) * 8 + j;
  int n = nt * 16 + (lane & 15);
  Wf[idx] = f2bf(W[k * Fo + n]);
}

// ---------------- GEMM layer1: h1[N,128](bf16) = x(fp32) @ W1, + alpha dots (fp32) ----------------
__global__ __launch_bounds__(256) void k_gemm1(const float* __restrict__ x,
                                               const unsigned short* __restrict__ Wf,
                                               const float* __restrict__ asrc,
                                               const float* __restrict__ adst,
                                               unsigned short* __restrict__ h1,
                                               float* __restrict__ as, float* __restrict__ ad) {
  __shared__ unsigned short tile[4][16 * 128];   // 16 KB, per-wave regions
  int wave = threadIdx.x >> 6, lane = threadIdx.x & 63;
  int strip = blockIdx.x * 4 + wave;
  if (strip >= kN / 16) return;
  int r0 = strip * 16;
  int m = lane & 15, quad = lane >> 4;
  const float4* xf = (const float4*)(x + (size_t)(r0 + m) * 128);   // 32 float4 per row
  short8 a0 = pack8(xf[quad * 2 + 0],  xf[quad * 2 + 1]);           // k-tile 0
  short8 a1 = pack8(xf[quad * 2 + 8],  xf[quad * 2 + 9]);           // k-tile 1
  short8 a2 = pack8(xf[quad * 2 + 16], xf[quad * 2 + 17]);          // k-tile 2
  short8 a3 = pack8(xf[quad * 2 + 24], xf[quad * 2 + 25]);          // k-tile 3
  const short8* wf = (const short8*)Wf;
  floatx4 acc[8];
#pragma unroll
  for (int nt = 0; nt < 8; ++nt) acc[nt] = floatx4{0.f, 0.f, 0.f, 0.f};
#pragma unroll
  for (int nt = 0; nt < 8; ++nt) {
    acc[nt] = __builtin_amdgcn_mfma_f32_16x16x32_bf16(a0, wf[(0 * 8 + nt) * 64 + lane], acc[nt], 0, 0, 0);
    acc[nt] = __builtin_amdgcn_mfma_f32_16x16x32_bf16(a1, wf[(1 * 8 + nt) * 64 + lane], acc[nt], 0, 0, 0);
    acc[nt] = __builtin_amdgcn_mfma_f32_16x16x32_bf16(a2, wf[(2 * 8 + nt) * 64 + lane], acc[nt], 0, 0, 0);
    acc[nt] = __builtin_amdgcn_mfma_f32_16x16x32_bf16(a3, wf[(3 * 8 + nt) * 64 + lane], acc[nt], 0, 0, 0);
  }
#pragma unroll
  for (int reg = 0; reg < 4; ++reg) {
    float s = 0.f, d = 0.f;
#pragma unroll
    for (int nt = 0; nt < 8; ++nt) {
      float v = acc[nt][reg];
      s += v * asrc[nt * 16 + m];
      d += v * adst[nt * 16 + m];
    }
#pragma unroll
    for (int off = 1; off < 16; off <<= 1) { s += __shfl_xor(s, off); d += __shfl_xor(d, off); }
    if (m == 0) { as[r0 + quad * 4 + reg] = s; ad[r0 + quad * 4 + reg] = d; }
  }
  unsigned short* tw = tile[wave];
#pragma unroll
  for (int nt = 0; nt < 8; ++nt)
#pragma unroll
    for (int reg = 0; reg < 4; ++reg)
      tw[(quad * 4 + reg) * 128 + nt * 16 + m] = f2bf(acc[nt][reg]);
  asm volatile("s_waitcnt lgkmcnt(0)" ::: "memory");   // wave-local LDS RAW
  const short8* tr = (const short8*)tw;
  short8* dstp = (short8*)(h1 + (size_t)r0 * 128);
#pragma unroll
  for (int sweep = 0; sweep < 4; ++sweep)
    dstp[sweep * 64 + lane] = tr[sweep * 64 + lane];
}

// ---------------- GEMM layer2: h2[N,64](bf16) = o1(bf16) @ W2, + alpha dots ----------------
__global__ __launch_bounds__(256) void k_gemm2(const unsigned short* __restrict__ o1,
                                               const unsigned short* __restrict__ Wf,
                                               const float* __restrict__ asrc,
                                               const float* __restrict__ adst,
                                               unsigned short* __restrict__ h2,
                                               float* __restrict__ as, float* __restrict__ ad) {
  __shared__ unsigned short tile[4][16 * 64];    // 8 KB
  int wave = threadIdx.x >> 6, lane = threadIdx.x & 63;
  int strip = blockIdx.x * 4 + wave;
  if (strip >= kN / 16) return;
  int r0 = strip * 16;
  int m = lane & 15, quad = lane >> 4;
  const short8* xs = (const short8*)(o1 + (size_t)(r0 + m) * 128);
  short8 a0 = xs[quad], a1 = xs[quad + 4], a2 = xs[quad + 8], a3 = xs[quad + 12];
  const short8* wf = (const short8*)Wf;
  floatx4 acc[4];
#pragma unroll
  for (int nt = 0; nt < 4; ++nt) acc[nt] = floatx4{0.f, 0.f, 0.f, 0.f};
#pragma unroll
  for (int nt = 0; nt < 4; ++nt) {
    acc[nt] = __builtin_amdgcn_mfma_f32_16x16x32_bf16(a0, wf[(0 * 4 + nt) * 64 + lane], acc[nt], 0, 0, 0);
    acc[nt] = __builtin_amdgcn_mfma_f32_16x16x32_bf16(a1, wf[(1 * 4 + nt) * 64 + lane], acc[nt], 0, 0, 0);
    acc[nt] = __builtin_amdgcn_mfma_f32_16x16x32_bf16(a2, wf[(2 * 4 + nt) * 64 + lane], acc[nt], 0, 0, 0);
    acc[nt] = __builtin_amdgcn_mfma_f32_16x16x32_bf16(a3, wf[(3 * 4 + nt) * 64 + lane], acc[nt], 0, 0, 0);
  }
#pragma unroll
  for (int reg = 0; reg < 4; ++reg) {
    float s = 0.f, d = 0.f;
#pragma unroll
    for (int nt = 0; nt < 4; ++nt) {
      float v = acc[nt][reg];
      s += v * asrc[nt * 16 + m];
      d += v * adst[nt * 16 + m];
    }
#pragma unroll
    for (int off = 1; off < 16; off <<= 1) { s += __shfl_xor(s, off); d += __shfl_xor(d, off); }
    if (m == 0) { as[r0 + quad * 4 + reg] = s; ad[r0 + quad * 4 + reg] = d; }
  }
  unsigned short* tw = tile[wave];
#pragma unroll
  for (int nt = 0; nt < 4; ++nt)
#pragma unroll
    for (int reg = 0; reg < 4; ++reg)
      tw[(quad * 4 + reg) * 64 + nt * 16 + m] = f2bf(acc[nt][reg]);
  asm volatile("s_waitcnt lgkmcnt(0)" ::: "memory");
  const short8* tr = (const short8*)tw;
  short8* dstp = (short8*)(h2 + (size_t)r0 * 64);
#pragma unroll
  for (int sweep = 0; sweep < 2; ++sweep)
    dstp[sweep * 64 + lane] = tr[sweep * 64 + lane];
}

// ---------------- aggregation: one wave per dst node ----------------
// Fast path (deg<=64, ~always): single-chunk exact softmax, (s,e) stay in
// registers; gather with dwordx2 sub-wave split (F=128: half-wave/edge,
// F=64: quarter-wave/edge). Fallback: chunked online-softmax (deg>64).
template <int F, bool MASKED>
__global__ __launch_bounds__(256) void k_agg(const unsigned short* __restrict__ h,
                                             const int* __restrict__ row_start,
                                             const int* __restrict__ col,
                                             const float* __restrict__ as,
                                             const float* __restrict__ ad,
                                             const float* __restrict__ bias,
                                             unsigned short* __restrict__ out,
                                             const int* __restrict__ maskIdx) {
  __shared__ int2 swb[4][64];
  int wave = threadIdx.x >> 6, lane = threadIdx.x & 63;
  int idx = blockIdx.x * 4 + wave;
  if (idx >= (MASKED ? kM : kN)) return;
  int n = MASKED ? maskIdx[idx] : idx;
  int nout = MASKED ? idx : n;
  int beg = row_start[n], end = row_start[n + 1];
  int deg = end - beg;
  float adn = ad[n];

  if (deg <= 64) {
    // ---- fast path ----
    int j = beg + lane;
    int s = 0; float e = -1e30f;
    if (j < end) {
      s = col[j];
      float t = as[s] + adn;
      e = t > 0.f ? t : kSlope * t;            // leaky_relu
    }
    float mx = e;
#pragma unroll
    for (int off = 32; off; off >>= 1) mx = fmaxf(mx, __shfl_xor(mx, off));
    float w0 = __expf(e - mx);                 // invalid lanes -> 0
    float l = w0;
#pragma unroll
    for (int off = 32; off; off >>= 1) l += __shfl_xor(l, off);
    float w = w0 * (1.f / l);
    swb[wave][lane] = int2{s, (int)__float_as_int(w)};
    asm volatile("s_waitcnt lgkmcnt(0)" ::: "memory");  // wave-local LDS RAW
    if (F == 128) {
      int half = lane >> 5, hl = lane & 31;
      float a0 = 0.f, a1 = 0.f, a2 = 0.f, a3 = 0.f;
      int cnt2 = (deg + 1) & ~1;
      for (int k = 0; k < cnt2; k += 2) {
        int2 p = swb[wave][k + half];
        float ww = __int_as_float(p.y);
        uint2 v = *(const uint2*)(h + (size_t)p.x * 128 + hl * 4);
        a0 += ww * bf2f((unsigned short)(v.x & 0xffffu));
        a1 += ww * bf2f((unsigned short)(v.x >> 16));
        a2 += ww * bf2f((unsigned short)(v.y & 0xffffu));
        a3 += ww * bf2f((unsigned short)(v.y >> 16));
      }
      a0 += __shfl_xor(a0, 32); a1 += __shfl_xor(a1, 32);
      a2 += __shfl_xor(a2, 32); a3 += __shfl_xor(a3, 32);
      if (half == 0) {
        float4 bb = ((const float4*)bias)[hl];
        float o0 = fmaxf(a0 + bb.x, 0.f), o1 = fmaxf(a1 + bb.y, 0.f);
        float o2 = fmaxf(a2 + bb.z, 0.f), o3 = fmaxf(a3 + bb.w, 0.f);
        uint2 pk;
        pk.x = ((unsigned int)f2bf(o1) << 16) | f2bf(o0);
        pk.y = ((unsigned int)f2bf(o3) << 16) | f2bf(o2);
        ((uint2*)(out + (size_t)nout * 128))[hl] = pk;
      }
    } else {
      int quarter = lane >> 4, ql = lane & 15;
      float a0 = 0.f, a1 = 0.f, a2 = 0.f, a3 = 0.f;
      int cnt4 = (deg + 3) & ~3;
      for (int k = 0; k < cnt4; k += 4) {
        int2 p = swb[wave][k + quarter];
        float ww = __int_as_float(p.y);
        uint2 v = *(const uint2*)(h + (size_t)p.x * 64 + ql * 4);
        a0 += ww * bf2f((unsigned short)(v.x & 0xffffu));
        a1 += ww * bf2f((unsigned short)(v.x >> 16));
        a2 += ww * bf2f((unsigned short)(v.y & 0xffffu));
        a3 += ww * bf2f((unsigned short)(v.y >> 16));
      }
      a0 += __shfl_xor(a0, 16); a1 += __shfl_xor(a1, 16);
      a2 += __shfl_xor(a2, 16); a3 += __shfl_xor(a3, 16);
      a0 += __shfl_xor(a0, 32); a1 += __shfl_xor(a1, 32);
      a2 += __shfl_xor(a2, 32); a3 += __shfl_xor(a3, 32);
      if (quarter == 0) {
        float4 bb = ((const float4*)bias)[ql];
        float o0 = fmaxf(a0 + bb.x, 0.f), o1 = fmaxf(a1 + bb.y, 0.f);
        float o2 = fmaxf(a2 + bb.z, 0.f), o3 = fmaxf(a3 + bb.w, 0.f);
        uint2 pk;
        pk.x = ((unsigned int)f2bf(o1) << 16) | f2bf(o0);
        pk.y = ((unsigned int)f2bf(o3) << 16) | f2bf(o2);
        ((uint2*)(out + (size_t)nout * 64))[ql] = pk;
      }
    }
    return;
  }

  // ---- fallback: chunked online softmax (deg > 64, essentially never) ----
  float m = -1e30f, l = 0.f;
  for (int j0 = beg; j0 < end; j0 += 64) {
    int j = j0 + lane;
    float e = -1e30f;
    if (j < end) {
      int s = col[j];
      float t = as[s] + adn;
      e = t > 0.f ? t : kSlope * t;
    }
    float cm = e;
#pragma unroll
    for (int off = 32; off; off >>= 1) cm = fmaxf(cm, __shfl_xor(cm, off));
    float w = __expf(e - cm);
    float cl = w;
#pragma unroll
    for (int off = 32; off; off >>= 1) cl += __shfl_xor(cl, off);
    float mn = fmaxf(m, cm);
    l = l * __expf(m - mn) + cl * __expf(cm - mn);
    m = mn;
  }
  float invl = 1.f / l;
  float a0 = 0.f, a1 = 0.f;
  int half = lane >> 5, hl = lane & 31;
  for (int j0 = beg; j0 < end; j0 += 64) {
    asm volatile("s_waitcnt lgkmcnt(0)" ::: "memory");
    int j = j0 + lane;
    if (j < end) {
      int s = col[j];
      float t = as[s] + adn;
      float e = t > 0.f ? t : kSlope * t;
      float w = __expf(e - m) * invl;
      swb[wave][lane] = int2{s, (int)__float_as_int(w)};
    }
    asm volatile("s_waitcnt lgkmcnt(0)" ::: "memory");
    int cntc = min(64, end - j0);
    if (F == 128) {
      for (int k = 0; k < cntc; ++k) {
        int2 p = swb[wave][k];
        float w = __int_as_float(p.y);
        unsigned int v = ((const unsigned int*)(h + (size_t)p.x * 128))[lane];
        a0 += w * bf2f((unsigned short)(v & 0xffffu));
        a1 += w * bf2f((unsigned short)(v >> 16));
      }
    } else {
      for (int k = 0; k < cntc; k += 2) {
        int kk = k + half;
        if (kk < cntc) {
          int2 p = swb[wave][kk];
          float w = __int_as_float(p.y);
          unsigned int v = ((const unsigned int*)(h + (size_t)p.x * 64))[hl];
          a0 += w * bf2f((unsigned short)(v & 0xffffu));
          a1 += w * bf2f((unsigned short)(v >> 16));
        }
      }
    }
  }
  if (F == 128) {
    float o0 = fmaxf(a0 + bias[2 * lane], 0.f);
    float o1 = fmaxf(a1 + bias[2 * lane + 1], 0.f);
    unsigned int packed = ((unsigned int)f2bf(o1) << 16) | f2bf(o0);
    ((unsigned int*)(out + (size_t)nout * 128))[lane] = packed;
  } else {
    a0 += __shfl_xor(a0, 32);
    a1 += __shfl_xor(a1, 32);
    if (half == 0) {
      float o0 = fmaxf(a0 + bias[2 * hl], 0.f);
      float o1 = fmaxf(a1 + bias[2 * hl + 1], 0.f);
      unsigned int packed = ((unsigned int)f2bf(o1) << 16) | f2bf(o0);
      ((unsigned int*)(out + (size_t)nout * 64))[hl] = packed;
    }
  }
}

// ---------------- FC head: per masked row (compact o2m), fused fc1(relu)+fc2 ----------------
__global__ __launch_bounds__(128) void k_fc(const unsigned short* __restrict__ o2m,
                                            const float* __restrict__ fc1w,
                                            const float* __restrict__ fc1b,
                                            const float* __restrict__ fc2w,
                                            const float* __restrict__ fc2b,
                                            float* __restrict__ out) {
  __shared__ float hm[64];
  __shared__ float z[128];
  int b = blockIdx.x, t = threadIdx.x;
  if (t < 64) hm[t] = bf2f(o2m[(size_t)b * 64 + t]);
  __syncthreads();
  float a = fc1b[t];
#pragma unroll 8
  for (int k = 0; k < 64; ++k) a += hm[k] * fc1w[k * 128 + t];
  z[t] = fmaxf(a, 0.f);
  __syncthreads();
  if (t < 10) {
    float o = fc2b[t];
#pragma unroll 8
    for (int k = 0; k < 128; ++k) o += z[k] * fc2w[k * 10 + t];
    out[(size_t)b * 10 + t] = o;
  }
}

extern "C" void kernel_launch(void* const* d_in, const int* in_sizes, int n_in,
                              void* d_out, int out_size, void* d_ws, size_t ws_size,
                              hipStream_t stream) {
  const float* x     = (const float*)d_in[0];
  const int*   ei    = (const int*)d_in[1];     // [2,E] as int32 (harness converts)
  const int*   mask  = (const int*)d_in[2];
  const float* W1    = (const float*)d_in[3];
  const float* asrc1 = (const float*)d_in[4];
  const float* adst1 = (const float*)d_in[5];
  const float* b1    = (const float*)d_in[6];
  const float* W2    = (const float*)d_in[7];
  const float* asrc2 = (const float*)d_in[8];
  const float* adst2 = (const float*)d_in[9];
  const float* b2    = (const float*)d_in[10];
  const float* fc1w  = (const float*)d_in[11];
  const float* fc1b  = (const float*)d_in[12];
  const float* fc2w  = (const float*)d_in[13];
  const float* fc2b  = (const float*)d_in[14];
  float* out = (float*)d_out;

  const int* esrc = ei;
  const int* edst = ei + kE;

  // -------- workspace layout (total ~70 MB) --------
  char* ws = (char*)d_ws;
  size_t off = 0;
  auto alloc = [&](size_t bytes) -> void* {
    void* p = ws + off;
    off = (off + bytes + 255) & ~(size_t)255;
    return p;
  };
  unsigned short* Wf1     = (unsigned short*)alloc(128 * 128 * 2);        // 32 KB
  unsigned short* Wf2     = (unsigned short*)alloc(128 * 64 * 2);         // 16 KB
  int*            rstart  = (int*)alloc((size_t)(kN + 1) * 4);            // 0.4 MB
  int*            bcursor = (int*)alloc((size_t)kNB * 4);                 // 3.1 KB
  int*            colBase = (int*)alloc((size_t)(kNB + 1) * 4);           // 3.1 KB
  float*          as1     = (float*)alloc((size_t)kN * 4);
  float*          ad1     = (float*)alloc((size_t)kN * 4);
  float*          as2     = (float*)alloc((size_t)kN * 4);
  float*          ad2     = (float*)alloc((size_t)kN * 4);                // 1.6 MB total
  int*            colidx  = (int*)alloc((size_t)kTotE * 4);               // 6.8 MB
  int*            pairs   = (int*)alloc((size_t)kNB * kBCap * 4);         // 9.6 MB
  unsigned short* h1      = (unsigned short*)alloc((size_t)kN * 128 * 2); // 25.6 MB
  unsigned short* o1      = (unsigned short*)alloc((size_t)kN * 128 * 2); // 25.6 MB
  // h2/o2m alias the h1 region (h1 dead after k_agg<128>)
  unsigned short* h2  = h1;                        // 12.8 MB
  unsigned short* o2m = h1 + (size_t)kN * 64;      // 2.56 MB (compact masked rows)
  (void)ws_size; (void)in_sizes; (void)n_in; (void)out_size;

  // CSR build, bucketed (ws re-poisoned every call -> rebuild each time)
  hipMemsetAsync(bcursor, 0, (size_t)kNB * 4, stream);
  k_bscatter<<<kSB, 256, 0, stream>>>(esrc, edst, bcursor, pairs);
  k_bscan<<<1, 1024, 0, stream>>>(bcursor, colBase, rstart);
  k_bucket_csr<<<kNB, 256, 0, stream>>>(pairs, bcursor, colBase, rstart, colidx);

  // Weight swizzle (fp32 -> bf16) for MFMA B-frags
  k_wprep<<<(128 * 128 + 255) / 256, 256, 0, stream>>>(W1, Wf1, 128, 128);
  k_wprep<<<(128 * 64 + 255) / 256, 256, 0, stream>>>(W2, Wf2, 128, 64);

  const int gemmBlocks = (kN / 16 + 3) / 4;   // 6250 strips, 4 waves/block
  const int nodeBlocks = (kN + 3) / 4;        // 1 wave per node
  const int maskBlocks = (kM + 3) / 4;        // 1 wave per masked node

  // Layer 1
  k_gemm1<<<gemmBlocks, 256, 0, stream>>>(x, Wf1, asrc1, adst1, h1, as1, ad1);
  k_agg<128, false><<<nodeBlocks, 256, 0, stream>>>(h1, rstart, colidx, as1, ad1, b1, o1, nullptr);
  // Layer 2 (h2 lives in the dead h1 region; aggregation only for masked rows)
  k_gemm2<<<gemmBlocks, 256, 0, stream>>>(o1, Wf2, asrc2, adst2, h2, as2, ad2);
  k_agg<64, true><<<maskBlocks, 256, 0, stream>>>(h2, rstart, colidx, as2, ad2, b2, o2m, mask);
  // FC head (compact rows)
  k_fc<<<kM, 128, 0, stream>>>(o2m, fc1w, fc1b, fc2w, fc2b, out);
}

// Round 8
// 289.390 us; speedup vs baseline: 3.5505x; 1.1263x over previous
//
#include <hip/hip_runtime.h>
#include <hip/hip_bf16.h>

constexpr int kN    = 100000;   // nodes
constexpr int kE    = 1600000;  // random edges
constexpr int kTotE = kE + kN;  // + self loops
constexpr int kM    = 20000;    // masked rows
constexpr float kSlope = 0.2f;

// bucketed CSR build: buckets of 128 consecutive dst nodes
constexpr int kNB   = (kN + 127) >> 7;          // 782 buckets
constexpr int kBCap = 3072;                      // per-bucket pair capacity (mean 2304)
constexpr int kEB   = 4096;                      // edge-stream elems per scatter block
constexpr int kSB   = (kTotE + kEB - 1) / kEB;   // 416 scatter blocks

typedef short short8  __attribute__((ext_vector_type(8)));
typedef float floatx4 __attribute__((ext_vector_type(4)));

__device__ __forceinline__ float bf2f(unsigned short u) {
  union { unsigned int i; float f; } v; v.i = ((unsigned int)u) << 16; return v.f;
}
__device__ __forceinline__ unsigned short f2bf(float f) {
  union { float f; unsigned int i; } v; v.f = f;
  unsigned int x = v.i;
  x += 0x7fffu + ((x >> 16) & 1u);   // RNE
  return (unsigned short)(x >> 16);
}
// HW packed f32->bf16 (v_cvt_pk_bf16_f32 on gfx950 via HIP intrinsic), RNE
__device__ __forceinline__ unsigned int packbf2(float lo, float hi) {
  __hip_bfloat162 h = __float22bfloat162_rn(float2{lo, hi});
  union { __hip_bfloat162 v; unsigned int u; } c; c.v = h; return c.u;
}
__device__ __forceinline__ unsigned short f2bf1(float f) {
  return (unsigned short)(packbf2(f, f) & 0xffffu);
}
__device__ __forceinline__ short8 pack8(float4 u, float4 v) {
  union { short8 s; unsigned int w[4]; } r;
  r.w[0] = packbf2(u.x, u.y); r.w[1] = packbf2(u.z, u.w);
  r.w[2] = packbf2(v.x, v.y); r.w[3] = packbf2(v.z, v.w);
  return r.s;
}

// ---------------- CSR build, bucketed ----------------
// pairs packed: (dst&127)<<17 | src   (src < 2^17, local node 7 bits)
__global__ __launch_bounds__(256) void k_bscatter(const int* __restrict__ src,
                                                  const int* __restrict__ dst,
                                                  int* __restrict__ bucketCursor,
                                                  int* __restrict__ pairs) {
  __shared__ int hist[kNB];
  __shared__ int runBase[kNB];
  __shared__ int binCur[kNB];
  int b = blockIdx.x, t = threadIdx.x;
  for (int i = t; i < kNB; i += 256) hist[i] = 0;
  __syncthreads();
  int i0 = b * kEB;
#pragma unroll
  for (int k = 0; k < kEB / 256; ++k) {
    int i = i0 + t + k * 256;
    if (i < kTotE) {
      int d = (i < kE) ? dst[i] : (i - kE);
      atomicAdd(&hist[d >> 7], 1);
    }
  }
  __syncthreads();
  for (int i = t; i < kNB; i += 256) {
    int c = hist[i];
    int base = -1;
    if (c) {
      base = atomicAdd(&bucketCursor[i], c);
      if (base + c > kBCap) base = -1;      // overflow guard (never expected)
    }
    runBase[i] = base;
    binCur[i] = 0;
  }
  __syncthreads();
#pragma unroll
  for (int k = 0; k < kEB / 256; ++k) {
    int i = i0 + t + k * 256;
    if (i < kTotE) {
      int s, d;
      if (i < kE) { s = src[i]; d = dst[i]; }
      else        { s = d = i - kE; }
      int bin = d >> 7;
      int lp = atomicAdd(&binCur[bin], 1);
      int rb = runBase[bin];
      if (rb >= 0) pairs[(size_t)bin * kBCap + rb + lp] = ((d & 127) << 17) | s;
    }
  }
}

__global__ __launch_bounds__(1024) void k_bscan(const int* __restrict__ bucketCursor,
                                                int* __restrict__ colBase,
                                                int* __restrict__ rstart) {
  __shared__ int sh[1024];
  int t = threadIdx.x;
  int v = (t < kNB) ? min(bucketCursor[t], kBCap) : 0;
  sh[t] = v;
  __syncthreads();
  for (int off = 1; off < 1024; off <<= 1) {
    int u = (t >= off) ? sh[t - off] : 0;
    __syncthreads();
    sh[t] += u;
    __syncthreads();
  }
  if (t < kNB) colBase[t] = sh[t] - v;        // exclusive prefix
  if (t == kNB - 1) { colBase[kNB] = sh[t]; rstart[kN] = sh[t]; }
}

__global__ __launch_bounds__(256) void k_bucket_csr(const int* __restrict__ pairs,
                                                    const int* __restrict__ bucketCursor,
                                                    const int* __restrict__ colBase,
                                                    int* __restrict__ rstart,
                                                    int* __restrict__ colidx) {
  __shared__ int pl[kBCap];                   // 12 KB
  __shared__ int colLDS[kBCap];               // 12 KB
  __shared__ int nhist[128], nstart[128], ncur[128], scanbuf[128];
  int b = blockIdx.x, t = threadIdx.x;
  int cnt  = min(bucketCursor[b], kBCap);
  int base = colBase[b];
  if (t < 128) { nhist[t] = 0; ncur[t] = 0; }
  __syncthreads();
  for (int j = t; j < cnt; j += 256) {
    int p = pairs[(size_t)b * kBCap + j];
    pl[j] = p;
    atomicAdd(&nhist[(p >> 17) & 127], 1);
  }
  __syncthreads();
  if (t < 128) scanbuf[t] = nhist[t];
  __syncthreads();
  for (int off = 1; off < 128; off <<= 1) {   // inclusive Hillis-Steele
    int u = (t < 128 && t >= off) ? scanbuf[t - off] : 0;
    __syncthreads();
    if (t < 128) scanbuf[t] += u;
    __syncthreads();
  }
  if (t < 128) nstart[t] = scanbuf[t] - nhist[t];   // exclusive
  __syncthreads();
  int nodes = min(128, kN - b * 128);
  if (t < nodes) rstart[b * 128 + t] = base + nstart[t];
  for (int j = t; j < cnt; j += 256) {
    int p = pl[j];
    int nl = (p >> 17) & 127;
    int lp = atomicAdd(&ncur[nl], 1);
    colLDS[nstart[nl] + lp] = p & 0x1FFFF;
  }
  __syncthreads();
  for (int j = t; j < cnt; j += 256)
    colidx[base + j] = colLDS[j];
}

// ---------------- weight pre-swizzle (fp32 -> bf16) into MFMA B-frag order ----------------
__global__ void k_wprep(const float* __restrict__ W,
                        unsigned short* __restrict__ Wf, int K, int Fo) {
  int idx = blockIdx.x * 256 + threadIdx.x;
  if (idx >= K * Fo) return;
  int j    = idx & 7;
  int lane = (idx >> 3) & 63;
  int t    = idx >> 9;
  int NT = Fo >> 4;
  int kt = t / NT, nt = t - kt * NT;
  int k = kt * 32 + ((lane >> 4) & 3) * 8 + j;
  int n = nt * 16 + (lane & 15);
  Wf[idx] = f2bf(W[k * Fo + n]);
}

// ---------------- GEMM layer1: h1[N,128](bf16) = x(fp32) @ W1, + alpha dots (fp32) ----------------
__global__ __launch_bounds__(256) void k_gemm1(const float* __restrict__ x,
                                               const unsigned short* __restrict__ Wf,
                                               const float* __restrict__ asrc,
                                               const float* __restrict__ adst,
                                               unsigned short* __restrict__ h1,
                                               float* __restrict__ as, float* __restrict__ ad) {
  __shared__ unsigned short tile[4][16 * 128];   // 16 KB, per-wave regions
  int wave = threadIdx.x >> 6, lane = threadIdx.x & 63;
  int strip = blockIdx.x * 4 + wave;
  if (strip >= kN / 16) return;
  int r0 = strip * 16;
  int m = lane & 15, quad = lane >> 4;
  const float4* xf = (const float4*)(x + (size_t)(r0 + m) * 128);   // 32 float4 per row
  short8 a0 = pack8(xf[quad * 2 + 0],  xf[quad * 2 + 1]);           // k-tile 0
  short8 a1 = pack8(xf[quad * 2 + 8],  xf[quad * 2 + 9]);           // k-tile 1
  short8 a2 = pack8(xf[quad * 2 + 16], xf[quad * 2 + 17]);          // k-tile 2
  short8 a3 = pack8(xf[quad * 2 + 24], xf[quad * 2 + 25]);          // k-tile 3
  const short8* wf = (const short8*)Wf;
  floatx4 acc[8];
#pragma unroll
  for (int nt = 0; nt < 8; ++nt) acc[nt] = floatx4{0.f, 0.f, 0.f, 0.f};
#pragma unroll
  for (int nt = 0; nt < 8; ++nt) {
    acc[nt] = __builtin_amdgcn_mfma_f32_16x16x32_bf16(a0, wf[(0 * 8 + nt) * 64 + lane], acc[nt], 0, 0, 0);
    acc[nt] = __builtin_amdgcn_mfma_f32_16x16x32_bf16(a1, wf[(1 * 8 + nt) * 64 + lane], acc[nt], 0, 0, 0);
    acc[nt] = __builtin_amdgcn_mfma_f32_16x16x32_bf16(a2, wf[(2 * 8 + nt) * 64 + lane], acc[nt], 0, 0, 0);
    acc[nt] = __builtin_amdgcn_mfma_f32_16x16x32_bf16(a3, wf[(3 * 8 + nt) * 64 + lane], acc[nt], 0, 0, 0);
  }
#pragma unroll
  for (int reg = 0; reg < 4; ++reg) {
    float s = 0.f, d = 0.f;
#pragma unroll
    for (int nt = 0; nt < 8; ++nt) {
      float v = acc[nt][reg];
      s += v * asrc[nt * 16 + m];
      d += v * adst[nt * 16 + m];
    }
#pragma unroll
    for (int off = 1; off < 16; off <<= 1) { s += __shfl_xor(s, off); d += __shfl_xor(d, off); }
    if (m == 0) { as[r0 + quad * 4 + reg] = s; ad[r0 + quad * 4 + reg] = d; }
  }
  unsigned short* tw = tile[wave];
#pragma unroll
  for (int nt = 0; nt < 8; ++nt)
#pragma unroll
    for (int reg = 0; reg < 4; ++reg)
      tw[(quad * 4 + reg) * 128 + nt * 16 + m] = f2bf1(acc[nt][reg]);
  asm volatile("s_waitcnt lgkmcnt(0)" ::: "memory");   // wave-local LDS RAW
  const short8* tr = (const short8*)tw;
  short8* dstp = (short8*)(h1 + (size_t)r0 * 128);
#pragma unroll
  for (int sweep = 0; sweep < 4; ++sweep)
    dstp[sweep * 64 + lane] = tr[sweep * 64 + lane];
}

// ---------------- GEMM layer2: h2[N,64](bf16) = o1(bf16) @ W2, + alpha dots ----------------
__global__ __launch_bounds__(256) void k_gemm2(const unsigned short* __restrict__ o1,
                                               const unsigned short* __restrict__ Wf,
                                               const float* __restrict__ asrc,
                                               const float* __restrict__ adst,
                                               unsigned short* __restrict__ h2,
                                               float* __restrict__ as, float* __restrict__ ad) {
  __shared__ unsigned short tile[4][16 * 64];    // 8 KB
  int wave = threadIdx.x >> 6, lane = threadIdx.x & 63;
  int strip = blockIdx.x * 4 + wave;
  if (strip >= kN / 16) return;
  int r0 = strip * 16;
  int m = lane & 15, quad = lane >> 4;
  const short8* xs = (const short8*)(o1 + (size_t)(r0 + m) * 128);
  short8 a0 = xs[quad], a1 = xs[quad + 4], a2 = xs[quad + 8], a3 = xs[quad + 12];
  const short8* wf = (const short8*)Wf;
  floatx4 acc[4];
#pragma unroll
  for (int nt = 0; nt < 4; ++nt) acc[nt] = floatx4{0.f, 0.f, 0.f, 0.f};
#pragma unroll
  for (int nt = 0; nt < 4; ++nt) {
    acc[nt] = __builtin_amdgcn_mfma_f32_16x16x32_bf16(a0, wf[(0 * 4 + nt) * 64 + lane], acc[nt], 0, 0, 0);
    acc[nt] = __builtin_amdgcn_mfma_f32_16x16x32_bf16(a1, wf[(1 * 4 + nt) * 64 + lane], acc[nt], 0, 0, 0);
    acc[nt] = __builtin_amdgcn_mfma_f32_16x16x32_bf16(a2, wf[(2 * 4 + nt) * 64 + lane], acc[nt], 0, 0, 0);
    acc[nt] = __builtin_amdgcn_mfma_f32_16x16x32_bf16(a3, wf[(3 * 4 + nt) * 64 + lane], acc[nt], 0, 0, 0);
  }
#pragma unroll
  for (int reg = 0; reg < 4; ++reg) {
    float s = 0.f, d = 0.f;
#pragma unroll
    for (int nt = 0; nt < 4; ++nt) {
      float v = acc[nt][reg];
      s += v * asrc[nt * 16 + m];
      d += v * adst[nt * 16 + m];
    }
#pragma unroll
    for (int off = 1; off < 16; off <<= 1) { s += __shfl_xor(s, off); d += __shfl_xor(d, off); }
    if (m == 0) { as[r0 + quad * 4 + reg] = s; ad[r0 + quad * 4 + reg] = d; }
  }
  unsigned short* tw = tile[wave];
#pragma unroll
  for (int nt = 0; nt < 4; ++nt)
#pragma unroll
    for (int reg = 0; reg < 4; ++reg)
      tw[(quad * 4 + reg) * 64 + nt * 16 + m] = f2bf1(acc[nt][reg]);
  asm volatile("s_waitcnt lgkmcnt(0)" ::: "memory");
  const short8* tr = (const short8*)tw;
  short8* dstp = (short8*)(h2 + (size_t)r0 * 64);
#pragma unroll
  for (int sweep = 0; sweep < 2; ++sweep)
    dstp[sweep * 64 + lane] = tr[sweep * 64 + lane];
}

// ---------------- aggregation: one wave per dst node ----------------
// Fast path (deg<=64, ~always): single-chunk exact softmax in registers;
// gather with dwordx4 sub-wave split (F=128: quarter-wave/edge ->4 edges/iter,
// F=64: eighth-wave/edge -> 8 edges/iter). Fallback: chunked online-softmax.
template <int F, bool MASKED>
__global__ __launch_bounds__(256) void k_agg(const unsigned short* __restrict__ h,
                                             const int* __restrict__ row_start,
                                             const int* __restrict__ col,
                                             const float* __restrict__ as,
                                             const float* __restrict__ ad,
                                             const float* __restrict__ bias,
                                             unsigned short* __restrict__ out,
                                             const int* __restrict__ maskIdx) {
  __shared__ int2 swb[4][64];
  int wave = threadIdx.x >> 6, lane = threadIdx.x & 63;
  int idx = blockIdx.x * 4 + wave;
  if (idx >= (MASKED ? kM : kN)) return;
  int n = MASKED ? maskIdx[idx] : idx;
  int nout = MASKED ? idx : n;
  int beg = row_start[n], end = row_start[n + 1];
  int deg = end - beg;
  float adn = ad[n];

  if (deg <= 64) {
    // ---- fast path: exact softmax, lane-parallel ----
    int j = beg + lane;
    int s = 0; float e = -1e30f;
    if (j < end) {
      s = col[j];
      float t = as[s] + adn;
      e = t > 0.f ? t : kSlope * t;            // leaky_relu
    }
    float mx = e;
#pragma unroll
    for (int off = 32; off; off >>= 1) mx = fmaxf(mx, __shfl_xor(mx, off));
    float w0 = __expf(e - mx);                 // invalid lanes -> 0
    float l = w0;
#pragma unroll
    for (int off = 32; off; off >>= 1) l += __shfl_xor(l, off);
    float w = w0 * (1.f / l);
    swb[wave][lane] = int2{s, (int)__float_as_int(w)};
    asm volatile("s_waitcnt lgkmcnt(0)" ::: "memory");  // wave-local LDS RAW
    float a[8];
#pragma unroll
    for (int i = 0; i < 8; ++i) a[i] = 0.f;
    if (F == 128) {
      int quarter = lane >> 4, ql = lane & 15;
      int cnt4 = (deg + 3) & ~3;
      for (int k = 0; k < cnt4; k += 4) {
        int2 p = swb[wave][k + quarter];
        float ww = __int_as_float(p.y);
        uint4 v = *(const uint4*)(h + (size_t)p.x * 128 + ql * 8);
        a[0] += ww * bf2f((unsigned short)(v.x & 0xffffu));
        a[1] += ww * bf2f((unsigned short)(v.x >> 16));
        a[2] += ww * bf2f((unsigned short)(v.y & 0xffffu));
        a[3] += ww * bf2f((unsigned short)(v.y >> 16));
        a[4] += ww * bf2f((unsigned short)(v.z & 0xffffu));
        a[5] += ww * bf2f((unsigned short)(v.z >> 16));
        a[6] += ww * bf2f((unsigned short)(v.w & 0xffffu));
        a[7] += ww * bf2f((unsigned short)(v.w >> 16));
      }
#pragma unroll
      for (int i = 0; i < 8; ++i) {
        a[i] += __shfl_xor(a[i], 16);
        a[i] += __shfl_xor(a[i], 32);
      }
      if (quarter == 0) {
        float4 b0 = ((const float4*)bias)[ql * 2];
        float4 b1 = ((const float4*)bias)[ql * 2 + 1];
        uint4 pk;
        pk.x = packbf2(fmaxf(a[0] + b0.x, 0.f), fmaxf(a[1] + b0.y, 0.f));
        pk.y = packbf2(fmaxf(a[2] + b0.z, 0.f), fmaxf(a[3] + b0.w, 0.f));
        pk.z = packbf2(fmaxf(a[4] + b1.x, 0.f), fmaxf(a[5] + b1.y, 0.f));
        pk.w = packbf2(fmaxf(a[6] + b1.z, 0.f), fmaxf(a[7] + b1.w, 0.f));
        ((uint4*)(out + (size_t)nout * 128))[ql] = pk;
      }
    } else {
      int eighth = lane >> 3, el = lane & 7;
      int cnt8 = (deg + 7) & ~7;
      for (int k = 0; k < cnt8; k += 8) {
        int2 p = swb[wave][k + eighth];
        float ww = __int_as_float(p.y);
        uint4 v = *(const uint4*)(h + (size_t)p.x * 64 + el * 8);
        a[0] += ww * bf2f((unsigned short)(v.x & 0xffffu));
        a[1] += ww * bf2f((unsigned short)(v.x >> 16));
        a[2] += ww * bf2f((unsigned short)(v.y & 0xffffu));
        a[3] += ww * bf2f((unsigned short)(v.y >> 16));
        a[4] += ww * bf2f((unsigned short)(v.z & 0xffffu));
        a[5] += ww * bf2f((unsigned short)(v.z >> 16));
        a[6] += ww * bf2f((unsigned short)(v.w & 0xffffu));
        a[7] += ww * bf2f((unsigned short)(v.w >> 16));
      }
#pragma unroll
      for (int i = 0; i < 8; ++i) {
        a[i] += __shfl_xor(a[i], 8);
        a[i] += __shfl_xor(a[i], 16);
        a[i] += __shfl_xor(a[i], 32);
      }
      if (eighth == 0) {
        float4 b0 = ((const float4*)bias)[el * 2];
        float4 b1 = ((const float4*)bias)[el * 2 + 1];
        uint4 pk;
        pk.x = packbf2(fmaxf(a[0] + b0.x, 0.f), fmaxf(a[1] + b0.y, 0.f));
        pk.y = packbf2(fmaxf(a[2] + b0.z, 0.f), fmaxf(a[3] + b0.w, 0.f));
        pk.z = packbf2(fmaxf(a[4] + b1.x, 0.f), fmaxf(a[5] + b1.y, 0.f));
        pk.w = packbf2(fmaxf(a[6] + b1.z, 0.f), fmaxf(a[7] + b1.w, 0.f));
        ((uint4*)(out + (size_t)nout * 64))[el] = pk;
      }
    }
    return;
  }

  // ---- fallback: chunked online softmax (deg > 64, essentially never) ----
  float m = -1e30f, l = 0.f;
  for (int j0 = beg; j0 < end; j0 += 64) {
    int j = j0 + lane;
    float e = -1e30f;
    if (j < end) {
      int s = col[j];
      float t = as[s] + adn;
      e = t > 0.f ? t : kSlope * t;
    }
    float cm = e;
#pragma unroll
    for (int off = 32; off; off >>= 1) cm = fmaxf(cm, __shfl_xor(cm, off));
    float w = __expf(e - cm);
    float cl = w;
#pragma unroll
    for (int off = 32; off; off >>= 1) cl += __shfl_xor(cl, off);
    float mn = fmaxf(m, cm);
    l = l * __expf(m - mn) + cl * __expf(cm - mn);
    m = mn;
  }
  float invl = 1.f / l;
  float a0 = 0.f, a1 = 0.f;
  int half = lane >> 5, hl = lane & 31;
  for (int j0 = beg; j0 < end; j0 += 64) {
    asm volatile("s_waitcnt lgkmcnt(0)" ::: "memory");
    int j = j0 + lane;
    if (j < end) {
      int s = col[j];
      float t = as[s] + adn;
      float e = t > 0.f ? t : kSlope * t;
      float w = __expf(e - m) * invl;
      swb[wave][lane] = int2{s, (int)__float_as_int(w)};
    }
    asm volatile("s_waitcnt lgkmcnt(0)" ::: "memory");
    int cntc = min(64, end - j0);
    if (F == 128) {
      for (int k = 0; k < cntc; ++k) {
        int2 p = swb[wave][k];
        float w = __int_as_float(p.y);
        unsigned int v = ((const unsigned int*)(h + (size_t)p.x * 128))[lane];
        a0 += w * bf2f((unsigned short)(v & 0xffffu));
        a1 += w * bf2f((unsigned short)(v >> 16));
      }
    } else {
      for (int k = 0; k < cntc; k += 2) {
        int kk = k + half;
        if (kk < cntc) {
          int2 p = swb[wave][kk];
          float w = __int_as_float(p.y);
          unsigned int v = ((const unsigned int*)(h + (size_t)p.x * 64))[hl];
          a0 += w * bf2f((unsigned short)(v & 0xffffu));
          a1 += w * bf2f((unsigned short)(v >> 16));
        }
      }
    }
  }
  if (F == 128) {
    float o0 = fmaxf(a0 + bias[2 * lane], 0.f);
    float o1 = fmaxf(a1 + bias[2 * lane + 1], 0.f);
    ((unsigned int*)(out + (size_t)nout * 128))[lane] = packbf2(o0, o1);
  } else {
    a0 += __shfl_xor(a0, 32);
    a1 += __shfl_xor(a1, 32);
    if (half == 0) {
      float o0 = fmaxf(a0 + bias[2 * hl], 0.f);
      float o1 = fmaxf(a1 + bias[2 * hl + 1], 0.f);
      ((unsigned int*)(out + (size_t)nout * 64))[hl] = packbf2(o0, o1);
    }
  }
}

// ---------------- FC1 via MFMA: z[kM,128](bf16) = relu(o2m[kM,64] @ fc1w + fc1b) ----------------
__global__ __launch_bounds__(256) void k_fc1(const unsigned short* __restrict__ o2m,
                                             const unsigned short* __restrict__ Wf,
                                             const float* __restrict__ fc1b,
                                             unsigned short* __restrict__ z) {
  __shared__ unsigned short tile[4][16 * 128];   // 16 KB
  int wave = threadIdx.x >> 6, lane = threadIdx.x & 63;
  int strip = blockIdx.x * 4 + wave;
  if (strip >= kM / 16) return;
  int r0 = strip * 16;
  int m = lane & 15, quad = lane >> 4;
  const short8* xs = (const short8*)(o2m + (size_t)(r0 + m) * 64);  // 8 short8 per row
  short8 a0 = xs[quad], a1 = xs[quad + 4];                          // k-tiles 0,1
  const short8* wf = (const short8*)Wf;
  floatx4 acc[8];
#pragma unroll
  for (int nt = 0; nt < 8; ++nt) acc[nt] = floatx4{0.f, 0.f, 0.f, 0.f};
#pragma unroll
  for (int nt = 0; nt < 8; ++nt) {
    acc[nt] = __builtin_amdgcn_mfma_f32_16x16x32_bf16(a0, wf[(0 * 8 + nt) * 64 + lane], acc[nt], 0, 0, 0);
    acc[nt] = __builtin_amdgcn_mfma_f32_16x16x32_bf16(a1, wf[(1 * 8 + nt) * 64 + lane], acc[nt], 0, 0, 0);
  }
  unsigned short* tw = tile[wave];
#pragma unroll
  for (int nt = 0; nt < 8; ++nt) {
    float bb = fc1b[nt * 16 + m];
#pragma unroll
    for (int reg = 0; reg < 4; ++reg)
      tw[(quad * 4 + reg) * 128 + nt * 16 + m] = f2bf1(fmaxf(acc[nt][reg] + bb, 0.f));
  }
  asm volatile("s_waitcnt lgkmcnt(0)" ::: "memory");
  const short8* tr = (const short8*)tw;
  short8* dstp = (short8*)(z + (size_t)r0 * 128);
#pragma unroll
  for (int sweep = 0; sweep < 4; ++sweep)
    dstp[sweep * 64 + lane] = tr[sweep * 64 + lane];
}

// ---------------- FC2: out[kM,10] = z @ fc2w + fc2b (weights register-resident) ----------------
__global__ __launch_bounds__(256) void k_fc2(const unsigned short* __restrict__ z,
                                             const float* __restrict__ fc2w,
                                             const float* __restrict__ fc2b,
                                             float* __restrict__ out) {
  int wave = threadIdx.x >> 6, lane = threadIdx.x & 63;
  int c = lane & 15, q = lane >> 4;          // c: output class (c<10), q: k-quarter
  bool active = c < 10;
  float wreg[32];
#pragma unroll
  for (int i = 0; i < 32; ++i)
    wreg[i] = active ? fc2w[(q * 32 + i) * 10 + c] : 0.f;
  for (int row = blockIdx.x * 4 + wave; row < kM; row += gridDim.x * 4) {
    const uint2* zr = (const uint2*)(z + (size_t)row * 128);
    float acc = 0.f;
#pragma unroll
    for (int i = 0; i < 8; ++i) {
      uint2 v = zr[q * 8 + i];               // 16 lanes broadcast same addr
      acc += bf2f((unsigned short)(v.x & 0xffffu)) * wreg[4 * i]
           + bf2f((unsigned short)(v.x >> 16))     * wreg[4 * i + 1]
           + bf2f((unsigned short)(v.y & 0xffffu)) * wreg[4 * i + 2]
           + bf2f((unsigned short)(v.y >> 16))     * wreg[4 * i + 3];
    }
    acc += __shfl_xor(acc, 16);
    acc += __shfl_xor(acc, 32);
    if (q == 0 && active) out[(size_t)row * 10 + c] = acc + fc2b[c];
  }
}

extern "C" void kernel_launch(void* const* d_in, const int* in_sizes, int n_in,
                              void* d_out, int out_size, void* d_ws, size_t ws_size,
                              hipStream_t stream) {
  const float* x     = (const float*)d_in[0];
  const int*   ei    = (const int*)d_in[1];     // [2,E] as int32 (harness converts)
  const int*   mask  = (const int*)d_in[2];
  const float* W1    = (const float*)d_in[3];
  const float* asrc1 = (const float*)d_in[4];
  const float* adst1 = (const float*)d_in[5];
  const float* b1    = (const float*)d_in[6];
  const float* W2    = (const float*)d_in[7];
  const float* asrc2 = (const float*)d_in[8];
  const float* adst2 = (const float*)d_in[9];
  const float* b2    = (const float*)d_in[10];
  const float* fc1w  = (const float*)d_in[11];
  const float* fc1b  = (const float*)d_in[12];
  const float* fc2w  = (const float*)d_in[13];
  const float* fc2b  = (const float*)d_in[14];
  float* out = (float*)d_out;

  const int* esrc = ei;
  const int* edst = ei + kE;

  // -------- workspace layout (total ~76 MB) --------
  char* ws = (char*)d_ws;
  size_t off = 0;
  auto alloc = [&](size_t bytes) -> void* {
    void* p = ws + off;
    off = (off + bytes + 255) & ~(size_t)255;
    return p;
  };
  unsigned short* Wf1     = (unsigned short*)alloc(128 * 128 * 2);        // 32 KB
  unsigned short* Wf2     = (unsigned short*)alloc(128 * 64 * 2);         // 16 KB
  unsigned short* Wf3     = (unsigned short*)alloc(64 * 128 * 2);         // 16 KB (fc1)
  int*            rstart  = (int*)alloc((size_t)(kN + 1) * 4);            // 0.4 MB
  int*            bcursor = (int*)alloc((size_t)kNB * 4);                 // 3.1 KB
  int*            colBase = (int*)alloc((size_t)(kNB + 1) * 4);           // 3.1 KB
  float*          as1     = (float*)alloc((size_t)kN * 4);
  float*          ad1     = (float*)alloc((size_t)kN * 4);
  float*          as2     = (float*)alloc((size_t)kN * 4);
  float*          ad2     = (float*)alloc((size_t)kN * 4);                // 1.6 MB total
  int*            colidx  = (int*)alloc((size_t)kTotE * 4);               // 6.8 MB
  int*            pairs   = (int*)alloc((size_t)kNB * kBCap * 4);         // 9.6 MB
  unsigned short* zbuf    = (unsigned short*)alloc((size_t)kM * 128 * 2); // 5.1 MB
  unsigned short* h1      = (unsigned short*)alloc((size_t)kN * 128 * 2); // 25.6 MB
  unsigned short* o1      = (unsigned short*)alloc((size_t)kN * 128 * 2); // 25.6 MB
  // h2/o2m alias the h1 region (h1 dead after k_agg<128>)
  unsigned short* h2  = h1;                        // 12.8 MB
  unsigned short* o2m = h1 + (size_t)kN * 64;      // 2.56 MB (compact masked rows)
  (void)ws_size; (void)in_sizes; (void)n_in; (void)out_size;

  // CSR build, bucketed (ws re-poisoned every call -> rebuild each time)
  hipMemsetAsync(bcursor, 0, (size_t)kNB * 4, stream);
  k_bscatter<<<kSB, 256, 0, stream>>>(esrc, edst, bcursor, pairs);
  k_bscan<<<1, 1024, 0, stream>>>(bcursor, colBase, rstart);
  k_bucket_csr<<<kNB, 256, 0, stream>>>(pairs, bcursor, colBase, rstart, colidx);

  // Weight swizzle (fp32 -> bf16) for MFMA B-frags
  k_wprep<<<(128 * 128 + 255) / 256, 256, 0, stream>>>(W1, Wf1, 128, 128);
  k_wprep<<<(128 * 64 + 255) / 256, 256, 0, stream>>>(W2, Wf2, 128, 64);
  k_wprep<<<(64 * 128 + 255) / 256, 256, 0, stream>>>(fc1w, Wf3, 64, 128);

  const int gemmBlocks = (kN / 16 + 3) / 4;   // 6250 strips, 4 waves/block
  const int nodeBlocks = (kN + 3) / 4;        // 1 wave per node
  const int maskBlocks = (kM + 3) / 4;        // 1 wave per masked node

  // Layer 1
  k_gemm1<<<gemmBlocks, 256, 0, stream>>>(x, Wf1, asrc1, adst1, h1, as1, ad1);
  k_agg<128, false><<<nodeBlocks, 256, 0, stream>>>(h1, rstart, colidx, as1, ad1, b1, o1, nullptr);
  // Layer 2 (h2 lives in the dead h1 region; aggregation only for masked rows)
  k_gemm2<<<gemmBlocks, 256, 0, stream>>>(o1, Wf2, asrc2, adst2, h2, as2, ad2);
  k_agg<64, true><<<maskBlocks, 256, 0, stream>>>(h2, rstart, colidx, as2, ad2, b2, o2m, mask);
  // FC head: MFMA fc1 + register-resident fc2
  k_fc1<<<(kM / 16 + 3) / 4, 256, 0, stream>>>(o2m, Wf3, fc1b, zbuf);
  k_fc2<<<512, 256, 0, stream>>>(zbuf, fc2w, fc2b, out);
}

// Round 9
// 259.185 us; speedup vs baseline: 3.9643x; 1.1165x over previous
//
#include <hip/hip_runtime.h>
#include <hip/hip_bf16.h>

constexpr int kN    = 100000;   // nodes
constexpr int kE    = 1600000;  // random edges
constexpr int kTotE = kE + kN;  // + self loops
constexpr int kM    = 20000;    // masked rows
constexpr float kSlope = 0.2f;

// bucketed CSR build: buckets of 128 consecutive dst nodes
constexpr int kNB   = (kN + 127) >> 7;          // 782 buckets
constexpr int kBCap = 3072;                      // per-bucket pair capacity (mean 2304)
constexpr int kEB   = 4096;                      // edge-stream elems per scatter block
constexpr int kSB   = (kTotE + kEB - 1) / kEB;   // 416 scatter blocks
constexpr int kG1B  = (kN / 16 + 3) / 4;         // 1563 gemm1 blocks

typedef short short8  __attribute__((ext_vector_type(8)));
typedef float floatx4 __attribute__((ext_vector_type(4)));

__device__ __forceinline__ float bf2f(unsigned short u) {
  union { unsigned int i; float f; } v; v.i = ((unsigned int)u) << 16; return v.f;
}
// HW packed f32->bf16 (v_cvt_pk_bf16_f32 on gfx950), RNE
__device__ __forceinline__ unsigned int packbf2(float lo, float hi) {
  __hip_bfloat162 h = __float22bfloat162_rn(float2{lo, hi});
  union { __hip_bfloat162 v; unsigned int u; } c; c.v = h; return c.u;
}
__device__ __forceinline__ unsigned short f2bf1(float f) {
  return (unsigned short)(packbf2(f, f) & 0xffffu);
}
__device__ __forceinline__ short8 pack8(float4 u, float4 v) {
  union { short8 s; unsigned int w[4]; } r;
  r.w[0] = packbf2(u.x, u.y); r.w[1] = packbf2(u.z, u.w);
  r.w[2] = packbf2(v.x, v.y); r.w[3] = packbf2(v.z, v.w);
  return r.s;
}

// ---------------- setup: 3 weight swizzles + zero bcursor, one dispatch ----------------
__device__ __forceinline__ void wprep1(int idx, const float* W, unsigned short* Wf,
                                       int Fo) {
  int j    = idx & 7;
  int lane = (idx >> 3) & 63;
  int t    = idx >> 9;
  int NT = Fo >> 4;
  int kt = t / NT, nt = t - kt * NT;
  int k = kt * 32 + ((lane >> 4) & 3) * 8 + j;
  int n = nt * 16 + (lane & 15);
  Wf[idx] = f2bf1(W[k * Fo + n]);
}

__global__ __launch_bounds__(256) void k_setup(const float* __restrict__ W1,
                                               const float* __restrict__ W2,
                                               const float* __restrict__ fc1w,
                                               unsigned short* __restrict__ Wf1,
                                               unsigned short* __restrict__ Wf2,
                                               unsigned short* __restrict__ Wf3,
                                               int* __restrict__ bcursor) {
  int gid = blockIdx.x * 256 + threadIdx.x;
  if (gid < kNB) bcursor[gid] = 0;
  if (gid < 16384)      wprep1(gid,          W1,   Wf1, 128);
  else if (gid < 24576) wprep1(gid - 16384,  W2,   Wf2, 64);
  else if (gid < 32768) wprep1(gid - 24576,  fc1w, Wf3, 128);
}

// ---------------- fat kernel: bscatter (blocks < kSB) U gemm1 (rest) ----------------
__global__ __launch_bounds__(256) void k_sg1(const int* __restrict__ esrc,
                                             const int* __restrict__ edst,
                                             int* __restrict__ bucketCursor,
                                             int* __restrict__ pairs,
                                             const float* __restrict__ x,
                                             const unsigned short* __restrict__ Wf,
                                             const float* __restrict__ asrc,
                                             const float* __restrict__ adst,
                                             unsigned short* __restrict__ h1,
                                             float* __restrict__ as, float* __restrict__ ad) {
  __shared__ int smemi[4096];                 // 16 KB overlay
  int t = threadIdx.x;
  if (blockIdx.x < kSB) {
    // ---- bscatter ----
    int* hist    = smemi;
    int* runBase = smemi + kNB;
    int* binCur  = smemi + 2 * kNB;
    int b = blockIdx.x;
    for (int i = t; i < kNB; i += 256) hist[i] = 0;
    __syncthreads();
    int i0 = b * kEB;
#pragma unroll
    for (int k = 0; k < kEB / 256; ++k) {
      int i = i0 + t + k * 256;
      if (i < kTotE) {
        int d = (i < kE) ? edst[i] : (i - kE);
        atomicAdd(&hist[d >> 7], 1);
      }
    }
    __syncthreads();
    for (int i = t; i < kNB; i += 256) {
      int c = hist[i];
      int base = -1;
      if (c) {
        base = atomicAdd(&bucketCursor[i], c);
        if (base + c > kBCap) base = -1;      // overflow guard (never expected)
      }
      runBase[i] = base;
      binCur[i] = 0;
    }
    __syncthreads();
#pragma unroll
    for (int k = 0; k < kEB / 256; ++k) {
      int i = i0 + t + k * 256;
      if (i < kTotE) {
        int s, d;
        if (i < kE) { s = esrc[i]; d = edst[i]; }
        else        { s = d = i - kE; }
        int bin = d >> 7;
        int lp = atomicAdd(&binCur[bin], 1);
        int rb = runBase[bin];
        if (rb >= 0) pairs[(size_t)bin * kBCap + rb + lp] = ((d & 127) << 17) | s;
      }
    }
    return;
  }
  // ---- gemm1: h1[N,128](bf16) = x(fp32) @ W1, + alpha dots ----
  int wave = t >> 6, lane = t & 63;
  int strip = (blockIdx.x - kSB) * 4 + wave;
  if (strip >= kN / 16) return;
  int r0 = strip * 16;
  int m = lane & 15, quad = lane >> 4;
  const float4* xf = (const float4*)(x + (size_t)(r0 + m) * 128);
  short8 a0 = pack8(xf[quad * 2 + 0],  xf[quad * 2 + 1]);
  short8 a1 = pack8(xf[quad * 2 + 8],  xf[quad * 2 + 9]);
  short8 a2 = pack8(xf[quad * 2 + 16], xf[quad * 2 + 17]);
  short8 a3 = pack8(xf[quad * 2 + 24], xf[quad * 2 + 25]);
  const short8* wf = (const short8*)Wf;
  floatx4 acc[8];
#pragma unroll
  for (int nt = 0; nt < 8; ++nt) acc[nt] = floatx4{0.f, 0.f, 0.f, 0.f};
#pragma unroll
  for (int nt = 0; nt < 8; ++nt) {
    acc[nt] = __builtin_amdgcn_mfma_f32_16x16x32_bf16(a0, wf[(0 * 8 + nt) * 64 + lane], acc[nt], 0, 0, 0);
    acc[nt] = __builtin_amdgcn_mfma_f32_16x16x32_bf16(a1, wf[(1 * 8 + nt) * 64 + lane], acc[nt], 0, 0, 0);
    acc[nt] = __builtin_amdgcn_mfma_f32_16x16x32_bf16(a2, wf[(2 * 8 + nt) * 64 + lane], acc[nt], 0, 0, 0);
    acc[nt] = __builtin_amdgcn_mfma_f32_16x16x32_bf16(a3, wf[(3 * 8 + nt) * 64 + lane], acc[nt], 0, 0, 0);
  }
#pragma unroll
  for (int reg = 0; reg < 4; ++reg) {
    float s = 0.f, d = 0.f;
#pragma unroll
    for (int nt = 0; nt < 8; ++nt) {
      float v = acc[nt][reg];
      s += v * asrc[nt * 16 + m];
      d += v * adst[nt * 16 + m];
    }
#pragma unroll
    for (int off = 1; off < 16; off <<= 1) { s += __shfl_xor(s, off); d += __shfl_xor(d, off); }
    if (m == 0) { as[r0 + quad * 4 + reg] = s; ad[r0 + quad * 4 + reg] = d; }
  }
  unsigned short* tw = (unsigned short*)smemi + wave * 2048;
#pragma unroll
  for (int nt = 0; nt < 8; ++nt)
#pragma unroll
    for (int reg = 0; reg < 4; ++reg)
      tw[(quad * 4 + reg) * 128 + nt * 16 + m] = f2bf1(acc[nt][reg]);
  asm volatile("s_waitcnt lgkmcnt(0)" ::: "memory");   // wave-local LDS RAW
  const short8* tr = (const short8*)tw;
  short8* dstp = (short8*)(h1 + (size_t)r0 * 128);
#pragma unroll
  for (int sweep = 0; sweep < 4; ++sweep)
    dstp[sweep * 64 + lane] = tr[sweep * 64 + lane];
}

// ---------------- bucket CSR finalize (in-place: colidx overwrites pairs) ----------------
__global__ __launch_bounds__(256) void k_bucket_csr(int* __restrict__ pairs,
                                                    const int* __restrict__ bucketCursor,
                                                    int* __restrict__ rstart,
                                                    int* __restrict__ degA) {
  __shared__ int pl[kBCap];                   // 12 KB
  __shared__ int colLDS[kBCap];               // 12 KB
  __shared__ int nhist[128], nstart[128], ncur[128], scanbuf[128];
  int b = blockIdx.x, t = threadIdx.x;
  int cnt  = min(bucketCursor[b], kBCap);
  int base = b * kBCap;                       // bucket-strided layout, no global scan
  if (t < 128) { nhist[t] = 0; ncur[t] = 0; }
  __syncthreads();
  for (int j = t; j < cnt; j += 256) {
    int p = pairs[(size_t)base + j];
    pl[j] = p;
    atomicAdd(&nhist[(p >> 17) & 127], 1);
  }
  __syncthreads();
  if (t < 128) scanbuf[t] = nhist[t];
  __syncthreads();
  for (int off = 1; off < 128; off <<= 1) {   // inclusive Hillis-Steele
    int u = (t < 128 && t >= off) ? scanbuf[t - off] : 0;
    __syncthreads();
    if (t < 128) scanbuf[t] += u;
    __syncthreads();
  }
  if (t < 128) nstart[t] = scanbuf[t] - nhist[t];   // exclusive
  __syncthreads();
  int nodes = min(128, kN - b * 128);
  if (t < nodes) {
    rstart[b * 128 + t] = base + nstart[t];
    degA[b * 128 + t]   = nhist[t];
  }
  for (int j = t; j < cnt; j += 256) {
    int p = pl[j];
    int nl = (p >> 17) & 127;
    int lp = atomicAdd(&ncur[nl], 1);
    colLDS[nstart[nl] + lp] = p & 0x1FFFF;
  }
  __syncthreads();
  for (int j = t; j < cnt; j += 256)
    pairs[(size_t)base + j] = colLDS[j];      // in-place: pairs becomes colidx
}

// ---------------- GEMM layer2: h2[N,64](bf16) = o1(bf16) @ W2, + alpha dots ----------------
__global__ __launch_bounds__(256) void k_gemm2(const unsigned short* __restrict__ o1,
                                               const unsigned short* __restrict__ Wf,
                                               const float* __restrict__ asrc,
                                               const float* __restrict__ adst,
                                               unsigned short* __restrict__ h2,
                                               float* __restrict__ as, float* __restrict__ ad) {
  __shared__ unsigned short tile[4][16 * 64];    // 8 KB
  int wave = threadIdx.x >> 6, lane = threadIdx.x & 63;
  int strip = blockIdx.x * 4 + wave;
  if (strip >= kN / 16) return;
  int r0 = strip * 16;
  int m = lane & 15, quad = lane >> 4;
  const short8* xs = (const short8*)(o1 + (size_t)(r0 + m) * 128);
  short8 a0 = xs[quad], a1 = xs[quad + 4], a2 = xs[quad + 8], a3 = xs[quad + 12];
  const short8* wf = (const short8*)Wf;
  floatx4 acc[4];
#pragma unroll
  for (int nt = 0; nt < 4; ++nt) acc[nt] = floatx4{0.f, 0.f, 0.f, 0.f};
#pragma unroll
  for (int nt = 0; nt < 4; ++nt) {
    acc[nt] = __builtin_amdgcn_mfma_f32_16x16x32_bf16(a0, wf[(0 * 4 + nt) * 64 + lane], acc[nt], 0, 0, 0);
    acc[nt] = __builtin_amdgcn_mfma_f32_16x16x32_bf16(a1, wf[(1 * 4 + nt) * 64 + lane], acc[nt], 0, 0, 0);
    acc[nt] = __builtin_amdgcn_mfma_f32_16x16x32_bf16(a2, wf[(2 * 4 + nt) * 64 + lane], acc[nt], 0, 0, 0);
    acc[nt] = __builtin_amdgcn_mfma_f32_16x16x32_bf16(a3, wf[(3 * 4 + nt) * 64 + lane], acc[nt], 0, 0, 0);
  }
#pragma unroll
  for (int reg = 0; reg < 4; ++reg) {
    float s = 0.f, d = 0.f;
#pragma unroll
    for (int nt = 0; nt < 4; ++nt) {
      float v = acc[nt][reg];
      s += v * asrc[nt * 16 + m];
      d += v * adst[nt * 16 + m];
    }
#pragma unroll
    for (int off = 1; off < 16; off <<= 1) { s += __shfl_xor(s, off); d += __shfl_xor(d, off); }
    if (m == 0) { as[r0 + quad * 4 + reg] = s; ad[r0 + quad * 4 + reg] = d; }
  }
  unsigned short* tw = tile[wave];
#pragma unroll
  for (int nt = 0; nt < 4; ++nt)
#pragma unroll
    for (int reg = 0; reg < 4; ++reg)
      tw[(quad * 4 + reg) * 64 + nt * 16 + m] = f2bf1(acc[nt][reg]);
  asm volatile("s_waitcnt lgkmcnt(0)" ::: "memory");
  const short8* tr = (const short8*)tw;
  short8* dstp = (short8*)(h2 + (size_t)r0 * 64);
#pragma unroll
  for (int sweep = 0; sweep < 2; ++sweep)
    dstp[sweep * 64 + lane] = tr[sweep * 64 + lane];
}

// ---------------- aggregation: one wave per dst node ----------------
// Fast path (deg<=64): exact softmax in registers; shfl-broadcast (s,w)
// (no LDS round-trip); 2 gathers in flight per iteration.
template <int F, bool MASKED>
__global__ __launch_bounds__(256) void k_agg(const unsigned short* __restrict__ h,
                                             const int* __restrict__ rstart,
                                             const int* __restrict__ degA,
                                             const int* __restrict__ col,
                                             const float* __restrict__ as,
                                             const float* __restrict__ ad,
                                             const float* __restrict__ bias,
                                             unsigned short* __restrict__ out,
                                             const int* __restrict__ maskIdx) {
  __shared__ int2 swb[4][64];                 // fallback only
  int wave = threadIdx.x >> 6, lane = threadIdx.x & 63;
  int idx = blockIdx.x * 4 + wave;
  if (idx >= (MASKED ? kM : kN)) return;
  int n = MASKED ? maskIdx[idx] : idx;
  int nout = MASKED ? idx : n;
  int beg = rstart[n];
  int deg = degA[n];
  float adn = ad[n];

  if (deg <= 64) {
    // ---- fast path ----
    int j = beg + lane;
    int s = 0; float e = -1e30f;
    if (lane < deg) {
      s = col[j];
      float t = as[s] + adn;
      e = t > 0.f ? t : kSlope * t;            // leaky_relu
    }
    float mx = e;
#pragma unroll
    for (int off = 32; off; off >>= 1) mx = fmaxf(mx, __shfl_xor(mx, off));
    float w0 = __expf(e - mx);                 // invalid lanes -> 0
    float l = w0;
#pragma unroll
    for (int off = 32; off; off >>= 1) l += __shfl_xor(l, off);
    float w = w0 * (1.f / l);
    float a[8];
#pragma unroll
    for (int i = 0; i < 8; ++i) a[i] = 0.f;
    if (F == 128) {
      int quarter = lane >> 4, ql = lane & 15;
      int cnt8 = (deg + 7) & ~7;
      for (int k = 0; k < cnt8; k += 8) {
        int i1 = k + quarter, i2 = i1 + 4;
        int   s1 = __shfl(s, i1), s2 = __shfl(s, i2);
        float w1 = __shfl(w, i1), w2 = __shfl(w, i2);
        uint4 v1 = *(const uint4*)(h + (size_t)s1 * 128 + ql * 8);
        uint4 v2 = *(const uint4*)(h + (size_t)s2 * 128 + ql * 8);
        a[0] += w1 * bf2f((unsigned short)(v1.x & 0xffffu));
        a[1] += w1 * bf2f((unsigned short)(v1.x >> 16));
        a[2] += w1 * bf2f((unsigned short)(v1.y & 0xffffu));
        a[3] += w1 * bf2f((unsigned short)(v1.y >> 16));
        a[4] += w1 * bf2f((unsigned short)(v1.z & 0xffffu));
        a[5] += w1 * bf2f((unsigned short)(v1.z >> 16));
        a[6] += w1 * bf2f((unsigned short)(v1.w & 0xffffu));
        a[7] += w1 * bf2f((unsigned short)(v1.w >> 16));
        a[0] += w2 * bf2f((unsigned short)(v2.x & 0xffffu));
        a[1] += w2 * bf2f((unsigned short)(v2.x >> 16));
        a[2] += w2 * bf2f((unsigned short)(v2.y & 0xffffu));
        a[3] += w2 * bf2f((unsigned short)(v2.y >> 16));
        a[4] += w2 * bf2f((unsigned short)(v2.z & 0xffffu));
        a[5] += w2 * bf2f((unsigned short)(v2.z >> 16));
        a[6] += w2 * bf2f((unsigned short)(v2.w & 0xffffu));
        a[7] += w2 * bf2f((unsigned short)(v2.w >> 16));
      }
#pragma unroll
      for (int i = 0; i < 8; ++i) {
        a[i] += __shfl_xor(a[i], 16);
        a[i] += __shfl_xor(a[i], 32);
      }
      if (quarter == 0) {
        float4 b0 = ((const float4*)bias)[ql * 2];
        float4 b1 = ((const float4*)bias)[ql * 2 + 1];
        uint4 pk;
        pk.x = packbf2(fmaxf(a[0] + b0.x, 0.f), fmaxf(a[1] + b0.y, 0.f));
        pk.y = packbf2(fmaxf(a[2] + b0.z, 0.f), fmaxf(a[3] + b0.w, 0.f));
        pk.z = packbf2(fmaxf(a[4] + b1.x, 0.f), fmaxf(a[5] + b1.y, 0.f));
        pk.w = packbf2(fmaxf(a[6] + b1.z, 0.f), fmaxf(a[7] + b1.w, 0.f));
        ((uint4*)(out + (size_t)nout * 128))[ql] = pk;
      }
    } else {
      int eighth = lane >> 3, el = lane & 7;
      int cnt16 = (deg + 15) & ~15;
      for (int k = 0; k < cnt16; k += 16) {
        int i1 = k + eighth, i2 = i1 + 8;
        int   s1 = __shfl(s, i1), s2 = __shfl(s, i2);
        float w1 = __shfl(w, i1), w2 = __shfl(w, i2);
        uint4 v1 = *(const uint4*)(h + (size_t)s1 * 64 + el * 8);
        uint4 v2 = *(const uint4*)(h + (size_t)s2 * 64 + el * 8);
        a[0] += w1 * bf2f((unsigned short)(v1.x & 0xffffu));
        a[1] += w1 * bf2f((unsigned short)(v1.x >> 16));
        a[2] += w1 * bf2f((unsigned short)(v1.y & 0xffffu));
        a[3] += w1 * bf2f((unsigned short)(v1.y >> 16));
        a[4] += w1 * bf2f((unsigned short)(v1.z & 0xffffu));
        a[5] += w1 * bf2f((unsigned short)(v1.z >> 16));
        a[6] += w1 * bf2f((unsigned short)(v1.w & 0xffffu));
        a[7] += w1 * bf2f((unsigned short)(v1.w >> 16));
        a[0] += w2 * bf2f((unsigned short)(v2.x & 0xffffu));
        a[1] += w2 * bf2f((unsigned short)(v2.x >> 16));
        a[2] += w2 * bf2f((unsigned short)(v2.y & 0xffffu));
        a[3] += w2 * bf2f((unsigned short)(v2.y >> 16));
        a[4] += w2 * bf2f((unsigned short)(v2.z & 0xffffu));
        a[5] += w2 * bf2f((unsigned short)(v2.z >> 16));
        a[6] += w2 * bf2f((unsigned short)(v2.w & 0xffffu));
        a[7] += w2 * bf2f((unsigned short)(v2.w >> 16));
      }
#pragma unroll
      for (int i = 0; i < 8; ++i) {
        a[i] += __shfl_xor(a[i], 8);
        a[i] += __shfl_xor(a[i], 16);
        a[i] += __shfl_xor(a[i], 32);
      }
      if (eighth == 0) {
        float4 b0 = ((const float4*)bias)[el * 2];
        float4 b1 = ((const float4*)bias)[el * 2 + 1];
        uint4 pk;
        pk.x = packbf2(fmaxf(a[0] + b0.x, 0.f), fmaxf(a[1] + b0.y, 0.f));
        pk.y = packbf2(fmaxf(a[2] + b0.z, 0.f), fmaxf(a[3] + b0.w, 0.f));
        pk.z = packbf2(fmaxf(a[4] + b1.x, 0.f), fmaxf(a[5] + b1.y, 0.f));
        pk.w = packbf2(fmaxf(a[6] + b1.z, 0.f), fmaxf(a[7] + b1.w, 0.f));
        ((uint4*)(out + (size_t)nout * 64))[el] = pk;
      }
    }
    return;
  }

  // ---- fallback: chunked online softmax (deg > 64, essentially never) ----
  int end = beg + deg;
  float m = -1e30f, l = 0.f;
  for (int j0 = beg; j0 < end; j0 += 64) {
    int j = j0 + lane;
    float e = -1e30f;
    if (j < end) {
      int s = col[j];
      float t = as[s] + adn;
      e = t > 0.f ? t : kSlope * t;
    }
    float cm = e;
#pragma unroll
    for (int off = 32; off; off >>= 1) cm = fmaxf(cm, __shfl_xor(cm, off));
    float w = __expf(e - cm);
    float cl = w;
#pragma unroll
    for (int off = 32; off; off >>= 1) cl += __shfl_xor(cl, off);
    float mn = fmaxf(m, cm);
    l = l * __expf(m - mn) + cl * __expf(cm - mn);
    m = mn;
  }
  float invl = 1.f / l;
  float a0 = 0.f, a1 = 0.f;
  int half = lane >> 5, hl = lane & 31;
  for (int j0 = beg; j0 < end; j0 += 64) {
    asm volatile("s_waitcnt lgkmcnt(0)" ::: "memory");
    int j = j0 + lane;
    if (j < end) {
      int s = col[j];
      float t = as[s] + adn;
      float e = t > 0.f ? t : kSlope * t;
      float w = __expf(e - m) * invl;
      swb[wave][lane] = int2{s, (int)__float_as_int(w)};
    }
    asm volatile("s_waitcnt lgkmcnt(0)" ::: "memory");
    int cntc = min(64, end - j0);
    if (F == 128) {
      for (int k = 0; k < cntc; ++k) {
        int2 p = swb[wave][k];
        float w = __int_as_float(p.y);
        unsigned int v = ((const unsigned int*)(h + (size_t)p.x * 128))[lane];
        a0 += w * bf2f((unsigned short)(v & 0xffffu));
        a1 += w * bf2f((unsigned short)(v >> 16));
      }
    } else {
      for (int k = 0; k < cntc; k += 2) {
        int kk = k + half;
        if (kk < cntc) {
          int2 p = swb[wave][kk];
          float w = __int_as_float(p.y);
          unsigned int v = ((const unsigned int*)(h + (size_t)p.x * 64))[hl];
          a0 += w * bf2f((unsigned short)(v & 0xffffu));
          a1 += w * bf2f((unsigned short)(v >> 16));
        }
      }
    }
  }
  if (F == 128) {
    float o0 = fmaxf(a0 + bias[2 * lane], 0.f);
    float o1 = fmaxf(a1 + bias[2 * lane + 1], 0.f);
    ((unsigned int*)(out + (size_t)nout * 128))[lane] = packbf2(o0, o1);
  } else {
    a0 += __shfl_xor(a0, 32);
    a1 += __shfl_xor(a1, 32);
    if (half == 0) {
      float o0 = fmaxf(a0 + bias[2 * hl], 0.f);
      float o1 = fmaxf(a1 + bias[2 * hl + 1], 0.f);
      ((unsigned int*)(out + (size_t)nout * 64))[hl] = packbf2(o0, o1);
    }
  }
}

// ---------------- fused FC head: fc1 (MFMA) -> LDS -> fc2 (register weights) ----------------
__global__ __launch_bounds__(256) void k_fc(const unsigned short* __restrict__ o2m,
                                            const unsigned short* __restrict__ Wf,
                                            const float* __restrict__ fc1b,
                                            const float* __restrict__ fc2w,
                                            const float* __restrict__ fc2b,
                                            float* __restrict__ out) {
  __shared__ unsigned short tile[4][16 * 128];   // 16 KB
  int wave = threadIdx.x >> 6, lane = threadIdx.x & 63;
  int strip = blockIdx.x * 4 + wave;
  if (strip >= kM / 16) return;
  int r0 = strip * 16;
  int m = lane & 15, quad = lane >> 4;
  const short8* xs = (const short8*)(o2m + (size_t)(r0 + m) * 64);
  short8 a0 = xs[quad], a1 = xs[quad + 4];
  const short8* wf = (const short8*)Wf;
  floatx4 acc[8];
#pragma unroll
  for (int nt = 0; nt < 8; ++nt) acc[nt] = floatx4{0.f, 0.f, 0.f, 0.f};
#pragma unroll
  for (int nt = 0; nt < 8; ++nt) {
    acc[nt] = __builtin_amdgcn_mfma_f32_16x16x32_bf16(a0, wf[(0 * 8 + nt) * 64 + lane], acc[nt], 0, 0, 0);
    acc[nt] = __builtin_amdgcn_mfma_f32_16x16x32_bf16(a1, wf[(1 * 8 + nt) * 64 + lane], acc[nt], 0, 0, 0);
  }
  unsigned short* tw = tile[wave];
#pragma unroll
  for (int nt = 0; nt < 8; ++nt) {
    float bb = fc1b[nt * 16 + m];
#pragma unroll
    for (int reg = 0; reg < 4; ++reg)
      tw[(quad * 4 + reg) * 128 + nt * 16 + m] = f2bf1(fmaxf(acc[nt][reg] + bb, 0.f));
  }
  asm volatile("s_waitcnt lgkmcnt(0)" ::: "memory");   // z tile visible to this wave
  // fc2: c = lane&15 (class, <10 active), q = lane>>4 (k-quarter)
  int c = lane & 15, q = lane >> 4;
  bool active = c < 10;
  float wreg[32];
#pragma unroll
  for (int i = 0; i < 32; ++i)
    wreg[i] = active ? fc2w[(q * 32 + i) * 10 + c] : 0.f;
  float bc = active ? fc2b[c] : 0.f;
  for (int r = 0; r < 16; ++r) {
    const uint2* zr = (const uint2*)(tw + r * 128 + q * 32);
    float acc2 = 0.f;
#pragma unroll
    for (int i = 0; i < 8; ++i) {
      uint2 v = zr[i];                       // 16 lanes broadcast same LDS addr
      acc2 += bf2f((unsigned short)(v.x & 0xffffu)) * wreg[4 * i]
            + bf2f((unsigned short)(v.x >> 16))     * wreg[4 * i + 1]
            + bf2f((unsigned short)(v.y & 0xffffu)) * wreg[4 * i + 2]
            + bf2f((unsigned short)(v.y >> 16))     * wreg[4 * i + 3];
    }
    acc2 += __shfl_xor(acc2, 16);
    acc2 += __shfl_xor(acc2, 32);
    if (q == 0 && active) out[(size_t)(r0 + r) * 10 + c] = acc2 + bc;
  }
}

extern "C" void kernel_launch(void* const* d_in, const int* in_sizes, int n_in,
                              void* d_out, int out_size, void* d_ws, size_t ws_size,
                              hipStream_t stream) {
  const float* x     = (const float*)d_in[0];
  const int*   ei    = (const int*)d_in[1];     // [2,E] as int32 (harness converts)
  const int*   mask  = (const int*)d_in[2];
  const float* W1    = (const float*)d_in[3];
  const float* asrc1 = (const float*)d_in[4];
  const float* adst1 = (const float*)d_in[5];
  const float* b1    = (const float*)d_in[6];
  const float* W2    = (const float*)d_in[7];
  const float* asrc2 = (const float*)d_in[8];
  const float* adst2 = (const float*)d_in[9];
  const float* b2    = (const float*)d_in[10];
  const float* fc1w  = (const float*)d_in[11];
  const float* fc1b  = (const float*)d_in[12];
  const float* fc2w  = (const float*)d_in[13];
  const float* fc2b  = (const float*)d_in[14];
  float* out = (float*)d_out;

  const int* esrc = ei;
  const int* edst = ei + kE;

  // -------- workspace layout (total ~72 MB) --------
  char* ws = (char*)d_ws;
  size_t off = 0;
  auto alloc = [&](size_t bytes) -> void* {
    void* p = ws + off;
    off = (off + bytes + 255) & ~(size_t)255;
    return p;
  };
  unsigned short* Wf1     = (unsigned short*)alloc(128 * 128 * 2);        // 32 KB
  unsigned short* Wf2     = (unsigned short*)alloc(128 * 64 * 2);         // 16 KB
  unsigned short* Wf3     = (unsigned short*)alloc(64 * 128 * 2);         // 16 KB (fc1)
  int*            rstart  = (int*)alloc((size_t)kN * 4);                  // 0.4 MB
  int*            degA    = (int*)alloc((size_t)kN * 4);                  // 0.4 MB
  int*            bcursor = (int*)alloc((size_t)kNB * 4);                 // 3.1 KB
  float*          as1     = (float*)alloc((size_t)kN * 4);
  float*          ad1     = (float*)alloc((size_t)kN * 4);
  float*          as2     = (float*)alloc((size_t)kN * 4);
  float*          ad2     = (float*)alloc((size_t)kN * 4);                // 1.6 MB total
  int*            pairs   = (int*)alloc((size_t)kNB * kBCap * 4);         // 9.6 MB (becomes colidx)
  unsigned short* h1      = (unsigned short*)alloc((size_t)kN * 128 * 2); // 25.6 MB
  unsigned short* o1      = (unsigned short*)alloc((size_t)kN * 128 * 2); // 25.6 MB
  // h2/o2m alias the h1 region (h1 dead after k_agg<128>)
  unsigned short* h2  = h1;                        // 12.8 MB
  unsigned short* o2m = h1 + (size_t)kN * 64;      // 2.56 MB (compact masked rows)
  (void)ws_size; (void)in_sizes; (void)n_in; (void)out_size;

  const int nodeBlocks = (kN + 3) / 4;
  const int maskBlocks = (kM + 3) / 4;

  // 1) setup: weight swizzles + zero bcursor
  k_setup<<<128, 256, 0, stream>>>(W1, W2, fc1w, Wf1, Wf2, Wf3, bcursor);
  // 2) fat kernel: edge scatter U gemm1
  k_sg1<<<kSB + kG1B, 256, 0, stream>>>(esrc, edst, bcursor, pairs,
                                        x, Wf1, asrc1, adst1, h1, as1, ad1);
  // 3) bucket CSR finalize (in-place)
  k_bucket_csr<<<kNB, 256, 0, stream>>>(pairs, bcursor, rstart, degA);
  // 4) layer-1 aggregation
  k_agg<128, false><<<nodeBlocks, 256, 0, stream>>>(h1, rstart, degA, pairs,
                                                    as1, ad1, b1, o1, nullptr);
  // 5) layer-2 GEMM
  k_gemm2<<<kG1B, 256, 0, stream>>>(o1, Wf2, asrc2, adst2, h2, as2, ad2);
  // 6) layer-2 aggregation, masked rows only
  k_agg<64, true><<<maskBlocks, 256, 0, stream>>>(h2, rstart, degA, pairs,
                                                  as2, ad2, b2, o2m, mask);
  // 7) fused FC head
  k_fc<<<(kM / 16 + 3) / 4, 256, 0, stream>>>(o2m, Wf3, fc1b, fc2w, fc2b, out);
}